// Round 16
// baseline (111.565 us; speedup 1.0000x reference)
//
#include <hip/hip_runtime.h>

#define EPS 1e-5f
#define TOKS 4096
#define NCF 8192
#define CCH 2048

#define PHI_BYTES ((size_t)8 * 32 * 8192 * 2)            // 4 MB bf16 phiT' (w folded)
#define LOGP_OFF  PHI_BYTES                              // float[512][16][32] = 1 MB
#define SSQP_OFF  (LOGP_OFF + (size_t)512 * 16 * 32 * 4) // float[512][16] = 32 KB
#define GATES_OFF (SSQP_OFF + (size_t)512 * 16 * 4)      // float[4096][32] = 512 KB
#define WS_NEED   (GATES_OFF + (size_t)TOKS * 32 * 4)

typedef __attribute__((ext_vector_type(8))) short bf16x8;
typedef __attribute__((ext_vector_type(4))) float f32x4;

__device__ __forceinline__ unsigned short f2bf(float f) {
  unsigned int u = __float_as_uint(f);
  u += 0x7FFFu + ((u >> 16) & 1u);
  return (unsigned short)(u >> 16);
}
__device__ __forceinline__ float bf2f(unsigned short s) {
  return __uint_as_float(((unsigned int)s) << 16);
}
__device__ __forceinline__ unsigned int pack2(float a, float b) {
  return (unsigned int)f2bf(a) | ((unsigned int)f2bf(b) << 16);
}

// ---------------- K0 v3: COALESCED transpose phi -> phiT' = w * phi (bf16, [A][32][8192]) ----------
// rows 0-3 = pre cols, 4-7 = post cols, 8-23 = res cols, 24-31 = zero.  [r15-proven + w fold]
__global__ __launch_bounds__(256)
void prep_phiT(const float* __restrict__ pre, const float* __restrict__ post,
               const float* __restrict__ res, const float* __restrict__ wnorm,
               unsigned short* __restrict__ phiT) {
  const int gid = blockIdx.x * 256 + threadIdx.x;    // 8 * 4096 threads
  const int a = gid >> 12;
  const int e0 = (gid & 4095) * 2;

  const float w0 = wnorm[(size_t)a * NCF + e0];
  const float w1 = wnorm[(size_t)a * NCF + e0 + 1];

  const float4 p0 = *(const float4*)(pre + ((size_t)a * NCF + e0) * 4);
  const float4 p1 = *(const float4*)(pre + ((size_t)a * NCF + e0) * 4 + 4);
  const float4 q0 = *(const float4*)(post + ((size_t)a * NCF + e0) * 4);
  const float4 q1 = *(const float4*)(post + ((size_t)a * NCF + e0) * 4 + 4);
  float r0[16], r1[16];
  #pragma unroll
  for (int j = 0; j < 4; ++j) {
    const float4 v = *(const float4*)(res + ((size_t)a * NCF + e0) * 16 + j * 4);
    r0[j*4+0] = v.x; r0[j*4+1] = v.y; r0[j*4+2] = v.z; r0[j*4+3] = v.w;
  }
  #pragma unroll
  for (int j = 0; j < 4; ++j) {
    const float4 v = *(const float4*)(res + ((size_t)a * NCF + e0) * 16 + 16 + j * 4);
    r1[j*4+0] = v.x; r1[j*4+1] = v.y; r1[j*4+2] = v.z; r1[j*4+3] = v.w;
  }

  unsigned short* base = phiT + (size_t)a * 32 * NCF + e0;
  const float pr0[4] = { p0.x, p0.y, p0.z, p0.w };
  const float pr1[4] = { p1.x, p1.y, p1.z, p1.w };
  const float po0[4] = { q0.x, q0.y, q0.z, q0.w };
  const float po1[4] = { q1.x, q1.y, q1.z, q1.w };
  #pragma unroll
  for (int r = 0; r < 4; ++r)
    *(unsigned int*)(base + (size_t)r * NCF) = pack2(w0 * pr0[r], w1 * pr1[r]);
  #pragma unroll
  for (int r = 0; r < 4; ++r)
    *(unsigned int*)(base + (size_t)(4 + r) * NCF) = pack2(w0 * po0[r], w1 * po1[r]);
  #pragma unroll
  for (int r = 0; r < 16; ++r)
    *(unsigned int*)(base + (size_t)(8 + r) * NCF) = pack2(w0 * r0[r], w1 * r1[r]);
  #pragma unroll
  for (int r = 24; r < 32; ++r)
    *(unsigned int*)(base + (size_t)r * NCF) = 0u;
}

// ---------------- K1: split-K logits. grid 512 = (tile 0..255, K-half 0..1) ----------------
// 512 threads = 8 waves; wave w owns cols [koff + w*512, +512) (2 t-iters of 256).
// __launch_bounds__(512,2): VGPR cap 128 (r12-measured) -> xv[16]=64 regs fits, NO spill.
// LDS ~70 KB -> 2 blocks/CU co-resident = 2x in-flight x loads vs r6.
__global__ __launch_bounds__(512, 2)
void logits_partial(const float* __restrict__ x,
                    const unsigned short* __restrict__ phiT,
                    const int* __restrict__ aidx_arr,
                    float* __restrict__ logP,    // [512][16][32]
                    float* __restrict__ ssqP) {  // [512][16]
  __shared__ unsigned short xs[8][16 * 264];   // per-wave staging tile (r6-proven pattern)
  __shared__ float logAcc[16][32];
  __shared__ float ssqAcc[16];

  const int tid = threadIdx.x;
  const int wave = tid >> 6, lane = tid & 63;
  const int tile = blockIdx.x >> 1;
  const int h = blockIdx.x & 1;
  const int tok0 = tile * 16;
  const int koff = h * 4096;
  const int aidx = aidx_arr[tok0 >> 10];

  logAcc[(tid >> 5) & 15][tid & 31] = 0.f;     // 512 threads cover 16x32
  if (tid < 16) ssqAcc[tid] = 0.f;
  __syncthreads();

  const float* xbase = x + (size_t)tok0 * NCF + koff + wave * 512 + lane * 4;
  const unsigned short* pBbase =
      phiT + ((size_t)aidx * 32 + (lane & 15)) * NCF + koff + wave * 512 + (lane >> 4) * 8;

  f32x4 acc0 = {0.f, 0.f, 0.f, 0.f};
  f32x4 acc1 = {0.f, 0.f, 0.f, 0.f};
  float ssq[16];
  #pragma unroll
  for (int r = 0; r < 16; ++r) ssq[r] = 0.f;

  for (int t = 0; t < 2; ++t) {
    float4 xv[16];
    #pragma unroll
    for (int r = 0; r < 16; ++r)
      xv[r] = *(const float4*)(xbase + (size_t)r * NCF + t * 256);
    #pragma unroll
    for (int r = 0; r < 16; ++r) {
      const float4 v = xv[r];
      ssq[r] += v.x * v.x + v.y * v.y + v.z * v.z + v.w * v.w;
      *(ushort4*)&xs[wave][r * 264 + lane * 4] =
          make_ushort4(f2bf(v.x), f2bf(v.y), f2bf(v.z), f2bf(v.w));
    }
    const unsigned short* pB = pBbase + t * 256;
    #pragma unroll
    for (int s = 0; s < 8; ++s) {
      bf16x8 a = *(const bf16x8*)&xs[wave][(lane & 15) * 264 + s * 32 + (lane >> 4) * 8];
      bf16x8 b0 = *(const bf16x8*)(pB + s * 32);
      bf16x8 b1 = *(const bf16x8*)(pB + 16 * NCF + s * 32);
      acc0 = __builtin_amdgcn_mfma_f32_16x16x32_bf16(a, b0, acc0, 0, 0, 0);
      acc1 = __builtin_amdgcn_mfma_f32_16x16x32_bf16(a, b1, acc1, 0, 0, 0);
    }
  }

  // ssq: shuffle-reduce then one atomic per (wave,row)
  #pragma unroll
  for (int r = 0; r < 16; ++r) {
    float v = ssq[r];
    #pragma unroll
    for (int m = 1; m <= 32; m <<= 1) v += __shfl_xor(v, m, 64);
    if (lane == 0) atomicAdd(&ssqAcc[r], v);
  }
  // C frags: D row=(lane>>4)*4+i, col=lane&15  [r6/r11-proven mapping]
  #pragma unroll
  for (int i = 0; i < 4; ++i) {
    atomicAdd(&logAcc[(lane >> 4) * 4 + i][lane & 15], acc0[i]);
    atomicAdd(&logAcc[(lane >> 4) * 4 + i][16 + (lane & 15)], acc1[i]);
  }
  __syncthreads();

  // write partials
  logP[(size_t)blockIdx.x * 512 + tid] = logAcc[(tid >> 5) & 15][tid & 31];
  if (tid < 16) ssqP[(size_t)blockIdx.x * 16 + tid] = ssqAcc[tid];
}

// ---------------- K2: combine halves + sigmoids + Sinkhorn -> gates[tok][32]  [r11-proven] ----------
__global__ __launch_bounds__(256)
void gates_kernel(const float* __restrict__ logP, const float* __restrict__ ssqP,
                  const float* __restrict__ b_pre, const float* __restrict__ b_post,
                  const float* __restrict__ b_res,
                  const float* __restrict__ a_pre, const float* __restrict__ a_post,
                  const float* __restrict__ a_res,
                  const int* __restrict__ aidx_arr,
                  float* __restrict__ gates) {
  const int tile = blockIdx.x;
  const int tid = threadIdx.x;
  const int tok = tid >> 4, cl = tid & 15;
  const int tok0 = tile * 16;
  const int aidx = aidx_arr[tok0 >> 10];

  const float* p0 = logP + (size_t)(tile * 2) * 512 + tok * 32;
  const float* p1 = logP + (size_t)(tile * 2 + 1) * 512 + tok * 32;
  const float Lg   = p0[cl] + p1[cl];
  const float Lres = p0[8 + cl] + p1[8 + cl];   // cols 8..23 = res logits 0..15
  const float ssqt = ssqP[(size_t)(tile * 2) * 16 + tok] + ssqP[(size_t)(tile * 2 + 1) * 16 + tok];
  const float invr = rsqrtf(ssqt * (1.f / NCF) + EPS);

  float* g = gates + (size_t)(tok0 + tok) * 32;
  if (cl < 4) {
    const float zp = a_pre[aidx] * Lg * invr + b_pre[(size_t)aidx * 4 + cl];
    g[cl] = 1.f / (1.f + __expf(-zp));
  } else if (cl < 8) {
    const float zq = a_post[aidx] * Lg * invr + b_post[(size_t)aidx * 4 + (cl - 4)];
    g[cl] = 2.f / (1.f + __expf(-zq));
  }
  const float tl = a_res[aidx] * Lres * invr + b_res[(size_t)aidx * 16 + cl];
  float m = __expf(tl);
  #pragma unroll
  for (int it = 0; it < 20; ++it) {
    float rs = m;
    rs += __shfl_xor(rs, 1, 64);
    rs += __shfl_xor(rs, 2, 64);
    m *= __builtin_amdgcn_rcpf(rs);
    float cs = m;
    cs += __shfl_xor(cs, 4, 64);
    cs += __shfl_xor(cs, 8, 64);
    m *= __builtin_amdgcn_rcpf(cs);
  }
  g[8 + cl] = m;
}

// ---------------- K3: streaming output pass  [r6-proven verbatim] ----------------
__global__ __launch_bounds__(256)
void out_pass(const float* __restrict__ x, const float* __restrict__ outp,
              const float* __restrict__ gates,
              float* __restrict__ agg, float* __restrict__ big) {
  const int tok = blockIdx.x;
  const int tid = threadIdx.x;
  const float* g = gates + (size_t)tok * 32;
  float hp[4], hq[4], M[16];
  #pragma unroll
  for (int i = 0; i < 4; ++i) { hp[i] = g[i]; hq[i] = g[4 + i]; }
  #pragma unroll
  for (int i = 0; i < 16; ++i) M[i] = g[8 + i];

  const float* xrow = x + (size_t)tok * NCF;
  const float* orow = outp + (size_t)tok * CCH;
  float* arow = agg + (size_t)tok * CCH;
  float* brow = big + (size_t)tok * NCF;

  #pragma unroll
  for (int rep = 0; rep < 2; ++rep) {
    const int c = rep * 1024 + tid * 4;
    float4 xv[4];
    #pragma unroll
    for (int j = 0; j < 4; ++j) xv[j] = *(const float4*)(xrow + j * CCH + c);
    const float4 ov = *(const float4*)(orow + c);

    f32x4 ag;
    ag.x = hp[0]*xv[0].x + hp[1]*xv[1].x + hp[2]*xv[2].x + hp[3]*xv[3].x;
    ag.y = hp[0]*xv[0].y + hp[1]*xv[1].y + hp[2]*xv[2].y + hp[3]*xv[3].y;
    ag.z = hp[0]*xv[0].z + hp[1]*xv[1].z + hp[2]*xv[2].z + hp[3]*xv[3].z;
    ag.w = hp[0]*xv[0].w + hp[1]*xv[1].w + hp[2]*xv[2].w + hp[3]*xv[3].w;
    __builtin_nontemporal_store(ag, (f32x4*)(arow + c));

    #pragma unroll
    for (int i = 0; i < 4; ++i) {
      const float m0 = M[i*4+0], m1 = M[i*4+1], m2 = M[i*4+2], m3 = M[i*4+3];
      f32x4 o;
      o.x = m0*xv[0].x + m1*xv[1].x + m2*xv[2].x + m3*xv[3].x + hq[i]*ov.x;
      o.y = m0*xv[0].y + m1*xv[1].y + m2*xv[2].y + m3*xv[3].y + hq[i]*ov.y;
      o.z = m0*xv[0].z + m1*xv[1].z + m2*xv[2].z + m3*xv[3].z + hq[i]*ov.z;
      o.w = m0*xv[0].w + m1*xv[1].w + m2*xv[2].w + m3*xv[3].w + hq[i]*ov.w;
      __builtin_nontemporal_store(o, (f32x4*)(brow + i * CCH + c));
    }
  }
}

// ---------------- fallback: round-1 fused kernel (used if ws too small) ----------------
__global__ __launch_bounds__(256, 4)
void lora_fused(const float* __restrict__ x, const float* __restrict__ outp,
                const float* __restrict__ wnorm, const float* __restrict__ phi_pre,
                const float* __restrict__ phi_post, const float* __restrict__ phi_res,
                const float* __restrict__ b_pre, const float* __restrict__ b_post,
                const float* __restrict__ b_res, const float* __restrict__ a_pre,
                const float* __restrict__ a_post, const float* __restrict__ a_res,
                const int* __restrict__ aidx_arr, float* __restrict__ agg_out,
                float* __restrict__ big_out) {
  __shared__ unsigned short xsb[2][NCF];
  __shared__ float scratch[4][52];
  __shared__ float red[52];
  __shared__ float Hpre[2][4], Hpost[2][4], Msm[2][16];
  const int tid = threadIdx.x;
  const int tok0 = blockIdx.x * 2;
  const int aidx = aidx_arr[tok0 >> 10];
  const float* xr0 = x + (size_t)tok0 * NCF;
  const float* xr1 = xr0 + NCF;
  const float* wr = wnorm + (size_t)aidx * NCF;
  const float* pp = phi_pre + (size_t)aidx * NCF * 4;
  const float* pq = phi_post + (size_t)aidx * NCF * 4;
  const float* pr = phi_res + (size_t)aidx * NCF * 16;
  float acc[50];
  #pragma unroll
  for (int i = 0; i < 50; ++i) acc[i] = 0.f;
  for (int k = 0; k < 8; ++k) {
    const int f0 = (k * 256 + tid) * 4;
    const float4 w4 = *(const float4*)(wr + f0);
    const float4 xa = *(const float4*)(xr0 + f0);
    const float4 xb = *(const float4*)(xr1 + f0);
    acc[0] += xa.x*xa.x + xa.y*xa.y + xa.z*xa.z + xa.w*xa.w;
    acc[25] += xb.x*xb.x + xb.y*xb.y + xb.z*xb.z + xb.w*xb.w;
    float xw0[4] = { xa.x*w4.x, xa.y*w4.y, xa.z*w4.z, xa.w*w4.w };
    float xw1[4] = { xb.x*w4.x, xb.y*w4.y, xb.z*w4.z, xb.w*w4.w };
    *(ushort4*)&xsb[0][f0] = make_ushort4(f2bf(xa.x), f2bf(xa.y), f2bf(xa.z), f2bf(xa.w));
    *(ushort4*)&xsb[1][f0] = make_ushort4(f2bf(xb.x), f2bf(xb.y), f2bf(xb.z), f2bf(xb.w));
    #pragma unroll
    for (int d = 0; d < 4; ++d) {
      const int f = f0 + d;
      const float a0 = xw0[d], a1 = xw1[d];
      float col[24];
      const float4 P = *(const float4*)(pp + ((size_t)f << 2));
      const float4 Q = *(const float4*)(pq + ((size_t)f << 2));
      const float4 R0 = *(const float4*)(pr + ((size_t)f << 4));
      const float4 R1 = *(const float4*)(pr + ((size_t)f << 4) + 4);
      const float4 R2 = *(const float4*)(pr + ((size_t)f << 4) + 8);
      const float4 R3 = *(const float4*)(pr + ((size_t)f << 4) + 12);
      col[0]=P.x; col[1]=P.y; col[2]=P.z; col[3]=P.w;
      col[4]=Q.x; col[5]=Q.y; col[6]=Q.z; col[7]=Q.w;
      col[8]=R0.x; col[9]=R0.y; col[10]=R0.z; col[11]=R0.w;
      col[12]=R1.x; col[13]=R1.y; col[14]=R1.z; col[15]=R1.w;
      col[16]=R2.x; col[17]=R2.y; col[18]=R2.z; col[19]=R2.w;
      col[20]=R3.x; col[21]=R3.y; col[22]=R3.z; col[23]=R3.w;
      #pragma unroll
      for (int c = 0; c < 24; ++c) { acc[1 + c] += a0 * col[c]; acc[26 + c] += a1 * col[c]; }
    }
  }
  #pragma unroll
  for (int m = 1; m <= 32; m <<= 1) {
    #pragma unroll
    for (int v = 0; v < 50; ++v) acc[v] += __shfl_xor(acc[v], m, 64);
  }
  const int wave = tid >> 6, lane = tid & 63;
  if (lane == 0) {
    #pragma unroll
    for (int v = 0; v < 50; ++v) scratch[wave][v] = acc[v];
  }
  __syncthreads();
  if (tid < 50) red[tid] = scratch[0][tid] + scratch[1][tid] + scratch[2][tid] + scratch[3][tid];
  __syncthreads();
  if (tid < 32) {
    const int t = tid >> 4, l = tid & 15;
    const float invr = rsqrtf(red[t * 25] * (1.f / NCF) + EPS);
    const float tl = a_res[aidx] * red[t * 25 + 1 + 8 + l] * invr + b_res[(size_t)aidx * 16 + l];
    float m = __expf(tl);
    #pragma unroll
    for (int it = 0; it < 20; ++it) {
      float rs = m; rs += __shfl_xor(rs, 1, 64); rs += __shfl_xor(rs, 2, 64);
      m *= __builtin_amdgcn_rcpf(rs);
      float cs = m; cs += __shfl_xor(cs, 4, 64); cs += __shfl_xor(cs, 8, 64);
      m *= __builtin_amdgcn_rcpf(cs);
    }
    Msm[t][l] = m;
  } else if (tid < 40) {
    const int q = tid - 32, t = q >> 2, n = q & 3;
    const float invr = rsqrtf(red[t * 25] * (1.f / NCF) + EPS);
    const float zp = a_pre[aidx] * red[t * 25 + 1 + n] * invr + b_pre[(size_t)aidx * 4 + n];
    const float zq = a_post[aidx] * red[t * 25 + 1 + 4 + n] * invr + b_post[(size_t)aidx * 4 + n];
    Hpre[t][n] = 1.f / (1.f + __expf(-zp));
    Hpost[t][n] = 2.f / (1.f + __expf(-zq));
  }
  __syncthreads();
  #pragma unroll
  for (int t = 0; t < 2; ++t) {
    const int tok = tok0 + t;
    const float* orow = outp + (size_t)tok * CCH;
    float* arow = agg_out + (size_t)tok * CCH;
    float* brow = big_out + (size_t)tok * 4 * CCH;
    const float hp0 = Hpre[t][0], hp1 = Hpre[t][1], hp2 = Hpre[t][2], hp3 = Hpre[t][3];
    float Mr[16];
    #pragma unroll
    for (int i = 0; i < 16; ++i) Mr[i] = Msm[t][i];
    const float hq[4] = { Hpost[t][0], Hpost[t][1], Hpost[t][2], Hpost[t][3] };
    #pragma unroll
    for (int w = 0; w < 2; ++w) {
      const int c0 = (w * 256 + tid) * 4;
      float4 xv[4];
      #pragma unroll
      for (int n = 0; n < 4; ++n) {
        const ushort4 u = *(const ushort4*)&xsb[t][n * CCH + c0];
        xv[n] = make_float4(bf2f(u.x), bf2f(u.y), bf2f(u.z), bf2f(u.w));
      }
      const float4 ov = *(const float4*)(orow + c0);
      float4 ag;
      ag.x = hp0*xv[0].x + hp1*xv[1].x + hp2*xv[2].x + hp3*xv[3].x;
      ag.y = hp0*xv[0].y + hp1*xv[1].y + hp2*xv[2].y + hp3*xv[3].y;
      ag.z = hp0*xv[0].z + hp1*xv[1].z + hp2*xv[2].z + hp3*xv[3].z;
      ag.w = hp0*xv[0].w + hp1*xv[1].w + hp2*xv[2].w + hp3*xv[3].w;
      *(float4*)(arow + c0) = ag;
      #pragma unroll
      for (int i = 0; i < 4; ++i) {
        const float m0 = Mr[i*4+0], m1 = Mr[i*4+1], m2 = Mr[i*4+2], m3 = Mr[i*4+3];
        float4 o;
        o.x = m0*xv[0].x + m1*xv[1].x + m2*xv[2].x + m3*xv[3].x + hq[i]*ov.x;
        o.y = m0*xv[0].y + m1*xv[1].y + m2*xv[2].y + m3*xv[3].y + hq[i]*ov.y;
        o.z = m0*xv[0].z + m1*xv[1].z + m2*xv[2].z + m3*xv[3].z + hq[i]*ov.z;
        o.w = m0*xv[0].w + m1*xv[1].w + m2*xv[2].w + m3*xv[3].w + hq[i]*ov.w;
        *(float4*)(brow + (size_t)i * CCH + c0) = o;
      }
    }
  }
}

extern "C" void kernel_launch(void* const* d_in, const int* in_sizes, int n_in,
                              void* d_out, int out_size, void* d_ws, size_t ws_size,
                              hipStream_t stream) {
  const float* x     = (const float*)d_in[0];
  const float* outp  = (const float*)d_in[1];
  const float* wnorm = (const float*)d_in[2];
  const float* ppre  = (const float*)d_in[3];
  const float* ppost = (const float*)d_in[4];
  const float* pres  = (const float*)d_in[5];
  const float* bpre  = (const float*)d_in[6];
  const float* bpost = (const float*)d_in[7];
  const float* bres  = (const float*)d_in[8];
  const float* apre  = (const float*)d_in[9];
  const float* apost = (const float*)d_in[10];
  const float* ares  = (const float*)d_in[11];
  const int*   aidx  = (const int*)d_in[12];

  float* agg = (float*)d_out;
  float* big = (float*)d_out + (size_t)TOKS * CCH;

  if (ws_size >= WS_NEED) {
    unsigned short* phiT = (unsigned short*)d_ws;
    float* logP  = (float*)((char*)d_ws + LOGP_OFF);
    float* ssqP  = (float*)((char*)d_ws + SSQP_OFF);
    float* gates = (float*)((char*)d_ws + GATES_OFF);
    hipLaunchKernelGGL(prep_phiT, dim3(128), dim3(256), 0, stream,
                       ppre, ppost, pres, wnorm, phiT);
    hipLaunchKernelGGL(logits_partial, dim3(512), dim3(512), 0, stream,
                       x, phiT, aidx, logP, ssqP);
    hipLaunchKernelGGL(gates_kernel, dim3(256), dim3(256), 0, stream,
                       logP, ssqP, bpre, bpost, bres, apre, apost, ares, aidx, gates);
    hipLaunchKernelGGL(out_pass, dim3(4096), dim3(256), 0, stream, x, outp, gates, agg, big);
  } else {
    hipLaunchKernelGGL(lora_fused, dim3(2048), dim3(256), 0, stream,
                       x, outp, wnorm, ppre, ppost, pres,
                       bpre, bpost, bres, apre, apost, ares, aidx, agg, big);
  }
}

// Round 18
// 106.250 us; speedup vs baseline: 1.0500x; 1.0500x over previous
//
#include <hip/hip_runtime.h>

#define EPS 1e-5f
#define TOKS 4096
#define NCF 8192
#define CCH 2048

#define PHI_BYTES ((size_t)8 * 32 * 8192 * 2)            // 4 MB bf16 phiT (no w fold)
#define GATES_OFF PHI_BYTES                              // float[4096][32] = 512 KB
#define WS_NEED   (GATES_OFF + (size_t)TOKS * 32 * 4)

typedef __attribute__((ext_vector_type(8))) short bf16x8;
typedef __attribute__((ext_vector_type(4))) float f32x4;

__device__ __forceinline__ unsigned short f2bf(float f) {
  unsigned int u = __float_as_uint(f);
  u += 0x7FFFu + ((u >> 16) & 1u);
  return (unsigned short)(u >> 16);
}
__device__ __forceinline__ float bf2f(unsigned short s) {
  return __uint_as_float(((unsigned int)s) << 16);
}
// packed RNE f32x2 -> bf16x2 in ONE VALU op (guide T12/m240: no builtin on gfx950, use asm)
__device__ __forceinline__ unsigned int packbf(float a, float b) {
  unsigned int r;
  asm("v_cvt_pk_bf16_f32 %0, %1, %2" : "=v"(r) : "v"(a), "v"(b));
  return r;
}

// ---------------- K0 v2: COALESCED transpose phi -> phiT (bf16, [A][32][8192]) [r15-proven] -------
// rows 0-3 = pre cols, 4-7 = post cols, 8-23 = res cols, 24-31 = zero.
__global__ __launch_bounds__(256)
void prep_phiT(const float* __restrict__ pre, const float* __restrict__ post,
               const float* __restrict__ res, unsigned short* __restrict__ phiT) {
  const int gid = blockIdx.x * 256 + threadIdx.x;    // 8 * 4096 threads
  const int a = gid >> 12;
  const int e0 = (gid & 4095) * 2;

  const float4 p0 = *(const float4*)(pre + ((size_t)a * NCF + e0) * 4);
  const float4 p1 = *(const float4*)(pre + ((size_t)a * NCF + e0) * 4 + 4);
  const float4 q0 = *(const float4*)(post + ((size_t)a * NCF + e0) * 4);
  const float4 q1 = *(const float4*)(post + ((size_t)a * NCF + e0) * 4 + 4);
  float r0[16], r1[16];
  #pragma unroll
  for (int j = 0; j < 4; ++j) {
    const float4 v = *(const float4*)(res + ((size_t)a * NCF + e0) * 16 + j * 4);
    r0[j*4+0] = v.x; r0[j*4+1] = v.y; r0[j*4+2] = v.z; r0[j*4+3] = v.w;
  }
  #pragma unroll
  for (int j = 0; j < 4; ++j) {
    const float4 v = *(const float4*)(res + ((size_t)a * NCF + e0) * 16 + 16 + j * 4);
    r1[j*4+0] = v.x; r1[j*4+1] = v.y; r1[j*4+2] = v.z; r1[j*4+3] = v.w;
  }

  unsigned short* base = phiT + (size_t)a * 32 * NCF + e0;
  const float pr0[4] = { p0.x, p0.y, p0.z, p0.w };
  const float pr1[4] = { p1.x, p1.y, p1.z, p1.w };
  const float po0[4] = { q0.x, q0.y, q0.z, q0.w };
  const float po1[4] = { q1.x, q1.y, q1.z, q1.w };
  #pragma unroll
  for (int r = 0; r < 4; ++r)
    *(unsigned int*)(base + (size_t)r * NCF) = packbf(pr0[r], pr1[r]);
  #pragma unroll
  for (int r = 0; r < 4; ++r)
    *(unsigned int*)(base + (size_t)(4 + r) * NCF) = packbf(po0[r], po1[r]);
  #pragma unroll
  for (int r = 0; r < 16; ++r)
    *(unsigned int*)(base + (size_t)(8 + r) * NCF) = packbf(r0[r], r1[r]);
  #pragma unroll
  for (int r = 24; r < 32; ++r)
    *(unsigned int*)(base + (size_t)r * NCF) = 0u;
}

// ---------------- K1: logits via MFMA + rms + sigmoid + Sinkhorn -> gates[tok][32] ----------------
// [r6-proven structure; staging pack now v_cvt_pk_bf16_f32]
// 512 threads = 8 waves; wave w owns K-slice [w*1024, (w+1)*1024) for a 16-token tile.
__global__ __launch_bounds__(512, 1)
void logits_gates(const float* __restrict__ x,
                  const float* __restrict__ wnorm,
                  const unsigned short* __restrict__ phiT,
                  const float* __restrict__ b_pre, const float* __restrict__ b_post,
                  const float* __restrict__ b_res,
                  const float* __restrict__ a_pre, const float* __restrict__ a_post,
                  const float* __restrict__ a_res,
                  const int* __restrict__ aidx_arr,
                  float* __restrict__ gates) {
  __shared__ unsigned short xs[8][16 * 264];   // per-wave bf16 tile [16 tok][256 feat], row pad 264
  __shared__ float logits_s[8][16][32];
  __shared__ float ssq_s[8][16];

  const int tid = threadIdx.x;
  const int wave = tid >> 6, lane = tid & 63;
  const int tok0 = blockIdx.x * 16;
  const int aidx = aidx_arr[tok0 >> 10];
  const int kbase = wave * 1024;

  const float* xbase = x + (size_t)tok0 * NCF + kbase + lane * 4;
  const float* wbase = wnorm + (size_t)aidx * NCF + kbase + lane * 4;
  const unsigned short* pBbase =
      phiT + ((size_t)aidx * 32 + (lane & 15)) * NCF + kbase + (lane >> 4) * 8;

  f32x4 acc0 = {0.f, 0.f, 0.f, 0.f};
  f32x4 acc1 = {0.f, 0.f, 0.f, 0.f};
  float ssq[16];
  #pragma unroll
  for (int r = 0; r < 16; ++r) ssq[r] = 0.f;

  float4 xr[16];
  #pragma unroll
  for (int r = 0; r < 16; ++r) xr[r] = *(const float4*)(xbase + (size_t)r * NCF);

  for (int t = 0; t < 4; ++t) {
    const float4 wv = *(const float4*)(wbase + t * 256);
    // stage: ssq + bf16(w*x) -> LDS (wave-private, no barrier needed)
    #pragma unroll
    for (int r = 0; r < 16; ++r) {
      const float4 xv = xr[r];
      ssq[r] += xv.x * xv.x + xv.y * xv.y + xv.z * xv.z + xv.w * xv.w;
      const unsigned int lo = packbf(xv.x * wv.x, xv.y * wv.y);
      const unsigned int hi = packbf(xv.z * wv.z, xv.w * wv.w);
      *(uint2*)&xs[wave][r * 264 + lane * 4] = make_uint2(lo, hi);
    }
    if (t < 3) {
      #pragma unroll
      for (int r = 0; r < 16; ++r)
        xr[r] = *(const float4*)(xbase + (size_t)r * NCF + (t + 1) * 256);
    }
    const unsigned short* pB = pBbase + t * 256;
    #pragma unroll
    for (int s = 0; s < 8; ++s) {
      bf16x8 a = *(const bf16x8*)&xs[wave][(lane & 15) * 264 + s * 32 + (lane >> 4) * 8];
      bf16x8 b0 = *(const bf16x8*)(pB + s * 32);
      bf16x8 b1 = *(const bf16x8*)(pB + 16 * NCF + s * 32);
      acc0 = __builtin_amdgcn_mfma_f32_16x16x32_bf16(a, b0, acc0, 0, 0, 0);
      acc1 = __builtin_amdgcn_mfma_f32_16x16x32_bf16(a, b1, acc1, 0, 0, 0);
    }
  }

  // ssq reduce across 64 lanes
  #pragma unroll
  for (int r = 0; r < 16; ++r) {
    float v = ssq[r];
    #pragma unroll
    for (int m = 1; m <= 32; m <<= 1) v += __shfl_xor(v, m, 64);
    if (lane == 0) ssq_s[wave][r] = v;
  }
  // C frags -> LDS: D[m=tok][n=col], m=(lane>>4)*4+i, n=lane&15
  #pragma unroll
  for (int i = 0; i < 4; ++i) {
    logits_s[wave][(lane >> 4) * 4 + i][lane & 15] = acc0[i];
    logits_s[wave][(lane >> 4) * 4 + i][16 + (lane & 15)] = acc1[i];
  }
  __syncthreads();

  if (tid < 256) {
    // per-thread: tok = tid>>4 (0..15), cl = tid&15
    const int tok = tid >> 4, cl = tid & 15;
    float L0 = 0.f, L16 = 0.f, ssqt = 0.f;
    #pragma unroll
    for (int w = 0; w < 8; ++w) {
      L0 += logits_s[w][tok][cl];
      L16 += logits_s[w][tok][16 + cl];
      ssqt += ssq_s[w][tok];
    }
    const float invr = rsqrtf(ssqt * (1.f / NCF) + EPS);

    float* g = gates + (size_t)(tok0 + tok) * 32;
    if (cl < 4) {
      const float zp = a_pre[aidx] * L0 * invr + b_pre[(size_t)aidx * 4 + cl];
      g[cl] = 1.f / (1.f + __expf(-zp));
    } else if (cl < 8) {
      const float zq = a_post[aidx] * L0 * invr + b_post[(size_t)aidx * 4 + (cl - 4)];
      g[cl] = 2.f / (1.f + __expf(-zq));
    }
    // gather res logits: res[cl] = col 8+cl
    const float resv = __shfl_xor((cl & 8) ? L0 : L16, 8, 64);
    const float tl = a_res[aidx] * resv * invr + b_res[(size_t)aidx * 16 + cl];
    float m = __expf(tl);
    #pragma unroll
    for (int it = 0; it < 20; ++it) {
      float rs = m;
      rs += __shfl_xor(rs, 1, 64);
      rs += __shfl_xor(rs, 2, 64);
      m *= __builtin_amdgcn_rcpf(rs);
      float cs = m;
      cs += __shfl_xor(cs, 4, 64);
      cs += __shfl_xor(cs, 8, 64);
      m *= __builtin_amdgcn_rcpf(cs);
    }
    g[8 + cl] = m;
  }
}

// ---------------- K3: streaming output pass  [r6-proven verbatim] ----------------
__global__ __launch_bounds__(256)
void out_pass(const float* __restrict__ x, const float* __restrict__ outp,
              const float* __restrict__ gates,
              float* __restrict__ agg, float* __restrict__ big) {
  const int tok = blockIdx.x;
  const int tid = threadIdx.x;
  const float* g = gates + (size_t)tok * 32;
  float hp[4], hq[4], M[16];
  #pragma unroll
  for (int i = 0; i < 4; ++i) { hp[i] = g[i]; hq[i] = g[4 + i]; }
  #pragma unroll
  for (int i = 0; i < 16; ++i) M[i] = g[8 + i];

  const float* xrow = x + (size_t)tok * NCF;
  const float* orow = outp + (size_t)tok * CCH;
  float* arow = agg + (size_t)tok * CCH;
  float* brow = big + (size_t)tok * NCF;

  #pragma unroll
  for (int rep = 0; rep < 2; ++rep) {
    const int c = rep * 1024 + tid * 4;
    float4 xv[4];
    #pragma unroll
    for (int j = 0; j < 4; ++j) xv[j] = *(const float4*)(xrow + j * CCH + c);
    const float4 ov = *(const float4*)(orow + c);

    f32x4 ag;
    ag.x = hp[0]*xv[0].x + hp[1]*xv[1].x + hp[2]*xv[2].x + hp[3]*xv[3].x;
    ag.y = hp[0]*xv[0].y + hp[1]*xv[1].y + hp[2]*xv[2].y + hp[3]*xv[3].y;
    ag.z = hp[0]*xv[0].z + hp[1]*xv[1].z + hp[2]*xv[2].z + hp[3]*xv[3].z;
    ag.w = hp[0]*xv[0].w + hp[1]*xv[1].w + hp[2]*xv[2].w + hp[3]*xv[3].w;
    __builtin_nontemporal_store(ag, (f32x4*)(arow + c));

    #pragma unroll
    for (int i = 0; i < 4; ++i) {
      const float m0 = M[i*4+0], m1 = M[i*4+1], m2 = M[i*4+2], m3 = M[i*4+3];
      f32x4 o;
      o.x = m0*xv[0].x + m1*xv[1].x + m2*xv[2].x + m3*xv[3].x + hq[i]*ov.x;
      o.y = m0*xv[0].y + m1*xv[1].y + m2*xv[2].y + m3*xv[3].y + hq[i]*ov.y;
      o.z = m0*xv[0].z + m1*xv[1].z + m2*xv[2].z + m3*xv[3].z + hq[i]*ov.z;
      o.w = m0*xv[0].w + m1*xv[1].w + m2*xv[2].w + m3*xv[3].w + hq[i]*ov.w;
      __builtin_nontemporal_store(o, (f32x4*)(brow + i * CCH + c));
    }
  }
}

// ---------------- fallback: round-1 fused kernel (used if ws too small) ----------------
__global__ __launch_bounds__(256, 4)
void lora_fused(const float* __restrict__ x, const float* __restrict__ outp,
                const float* __restrict__ wnorm, const float* __restrict__ phi_pre,
                const float* __restrict__ phi_post, const float* __restrict__ phi_res,
                const float* __restrict__ b_pre, const float* __restrict__ b_post,
                const float* __restrict__ b_res, const float* __restrict__ a_pre,
                const float* __restrict__ a_post, const float* __restrict__ a_res,
                const int* __restrict__ aidx_arr, float* __restrict__ agg_out,
                float* __restrict__ big_out) {
  __shared__ unsigned short xsb[2][NCF];
  __shared__ float scratch[4][52];
  __shared__ float red[52];
  __shared__ float Hpre[2][4], Hpost[2][4], Msm[2][16];
  const int tid = threadIdx.x;
  const int tok0 = blockIdx.x * 2;
  const int aidx = aidx_arr[tok0 >> 10];
  const float* xr0 = x + (size_t)tok0 * NCF;
  const float* xr1 = xr0 + NCF;
  const float* wr = wnorm + (size_t)aidx * NCF;
  const float* pp = phi_pre + (size_t)aidx * NCF * 4;
  const float* pq = phi_post + (size_t)aidx * NCF * 4;
  const float* pr = phi_res + (size_t)aidx * NCF * 16;
  float acc[50];
  #pragma unroll
  for (int i = 0; i < 50; ++i) acc[i] = 0.f;
  for (int k = 0; k < 8; ++k) {
    const int f0 = (k * 256 + tid) * 4;
    const float4 w4 = *(const float4*)(wr + f0);
    const float4 xa = *(const float4*)(xr0 + f0);
    const float4 xb = *(const float4*)(xr1 + f0);
    acc[0] += xa.x*xa.x + xa.y*xa.y + xa.z*xa.z + xa.w*xa.w;
    acc[25] += xb.x*xb.x + xb.y*xb.y + xb.z*xb.z + xb.w*xb.w;
    float xw0[4] = { xa.x*w4.x, xa.y*w4.y, xa.z*w4.z, xa.w*w4.w };
    float xw1[4] = { xb.x*w4.x, xb.y*w4.y, xb.z*w4.z, xb.w*w4.w };
    *(ushort4*)&xsb[0][f0] = make_ushort4(f2bf(xa.x), f2bf(xa.y), f2bf(xa.z), f2bf(xa.w));
    *(ushort4*)&xsb[1][f0] = make_ushort4(f2bf(xb.x), f2bf(xb.y), f2bf(xb.z), f2bf(xb.w));
    #pragma unroll
    for (int d = 0; d < 4; ++d) {
      const int f = f0 + d;
      const float a0 = xw0[d], a1 = xw1[d];
      float col[24];
      const float4 P = *(const float4*)(pp + ((size_t)f << 2));
      const float4 Q = *(const float4*)(pq + ((size_t)f << 2));
      const float4 R0 = *(const float4*)(pr + ((size_t)f << 4));
      const float4 R1 = *(const float4*)(pr + ((size_t)f << 4) + 4);
      const float4 R2 = *(const float4*)(pr + ((size_t)f << 4) + 8);
      const float4 R3 = *(const float4*)(pr + ((size_t)f << 4) + 12);
      col[0]=P.x; col[1]=P.y; col[2]=P.z; col[3]=P.w;
      col[4]=Q.x; col[5]=Q.y; col[6]=Q.z; col[7]=Q.w;
      col[8]=R0.x; col[9]=R0.y; col[10]=R0.z; col[11]=R0.w;
      col[12]=R1.x; col[13]=R1.y; col[14]=R1.z; col[15]=R1.w;
      col[16]=R2.x; col[17]=R2.y; col[18]=R2.z; col[19]=R2.w;
      col[20]=R3.x; col[21]=R3.y; col[22]=R3.z; col[23]=R3.w;
      #pragma unroll
      for (int c = 0; c < 24; ++c) { acc[1 + c] += a0 * col[c]; acc[26 + c] += a1 * col[c]; }
    }
  }
  #pragma unroll
  for (int m = 1; m <= 32; m <<= 1) {
    #pragma unroll
    for (int v = 0; v < 50; ++v) acc[v] += __shfl_xor(acc[v], m, 64);
  }
  const int wave = tid >> 6, lane = tid & 63;
  if (lane == 0) {
    #pragma unroll
    for (int v = 0; v < 50; ++v) scratch[wave][v] = acc[v];
  }
  __syncthreads();
  if (tid < 50) red[tid] = scratch[0][tid] + scratch[1][tid] + scratch[2][tid] + scratch[3][tid];
  __syncthreads();
  if (tid < 32) {
    const int t = tid >> 4, l = tid & 15;
    const float invr = rsqrtf(red[t * 25] * (1.f / NCF) + EPS);
    const float tl = a_res[aidx] * red[t * 25 + 1 + 8 + l] * invr + b_res[(size_t)aidx * 16 + l];
    float m = __expf(tl);
    #pragma unroll
    for (int it = 0; it < 20; ++it) {
      float rs = m; rs += __shfl_xor(rs, 1, 64); rs += __shfl_xor(rs, 2, 64);
      m *= __builtin_amdgcn_rcpf(rs);
      float cs = m; cs += __shfl_xor(cs, 4, 64); cs += __shfl_xor(cs, 8, 64);
      m *= __builtin_amdgcn_rcpf(cs);
    }
    Msm[t][l] = m;
  } else if (tid < 40) {
    const int q = tid - 32, t = q >> 2, n = q & 3;
    const float invr = rsqrtf(red[t * 25] * (1.f / NCF) + EPS);
    const float zp = a_pre[aidx] * red[t * 25 + 1 + n] * invr + b_pre[(size_t)aidx * 4 + n];
    const float zq = a_post[aidx] * red[t * 25 + 1 + 4 + n] * invr + b_post[(size_t)aidx * 4 + n];
    Hpre[t][n] = 1.f / (1.f + __expf(-zp));
    Hpost[t][n] = 2.f / (1.f + __expf(-zq));
  }
  __syncthreads();
  #pragma unroll
  for (int t = 0; t < 2; ++t) {
    const int tok = tok0 + t;
    const float* orow = outp + (size_t)tok * CCH;
    float* arow = agg_out + (size_t)tok * CCH;
    float* brow = big_out + (size_t)tok * 4 * CCH;
    const float hp0 = Hpre[t][0], hp1 = Hpre[t][1], hp2 = Hpre[t][2], hp3 = Hpre[t][3];
    float Mr[16];
    #pragma unroll
    for (int i = 0; i < 16; ++i) Mr[i] = Msm[t][i];
    const float hq[4] = { Hpost[t][0], Hpost[t][1], Hpost[t][2], Hpost[t][3] };
    #pragma unroll
    for (int w = 0; w < 2; ++w) {
      const int c0 = (w * 256 + tid) * 4;
      float4 xv[4];
      #pragma unroll
      for (int n = 0; n < 4; ++n) {
        const ushort4 u = *(const ushort4*)&xsb[t][n * CCH + c0];
        xv[n] = make_float4(bf2f(u.x), bf2f(u.y), bf2f(u.z), bf2f(u.w));
      }
      const float4 ov = *(const float4*)(orow + c0);
      float4 ag;
      ag.x = hp0*xv[0].x + hp1*xv[1].x + hp2*xv[2].x + hp3*xv[3].x;
      ag.y = hp0*xv[0].y + hp1*xv[1].y + hp2*xv[2].y + hp3*xv[3].y;
      ag.z = hp0*xv[0].z + hp1*xv[1].z + hp2*xv[2].z + hp3*xv[3].z;
      ag.w = hp0*xv[0].w + hp1*xv[1].w + hp2*xv[2].w + hp3*xv[3].w;
      *(float4*)(arow + c0) = ag;
      #pragma unroll
      for (int i = 0; i < 4; ++i) {
        const float m0 = Mr[i*4+0], m1 = Mr[i*4+1], m2 = Mr[i*4+2], m3 = Mr[i*4+3];
        float4 o;
        o.x = m0*xv[0].x + m1*xv[1].x + m2*xv[2].x + m3*xv[3].x + hq[i]*ov.x;
        o.y = m0*xv[0].y + m1*xv[1].y + m2*xv[2].y + m3*xv[3].y + hq[i]*ov.y;
        o.z = m0*xv[0].z + m1*xv[1].z + m2*xv[2].z + m3*xv[3].z + hq[i]*ov.z;
        o.w = m0*xv[0].w + m1*xv[1].w + m2*xv[2].w + m3*xv[3].w + hq[i]*ov.w;
        *(float4*)(brow + (size_t)i * CCH + c0) = o;
      }
    }
  }
}

extern "C" void kernel_launch(void* const* d_in, const int* in_sizes, int n_in,
                              void* d_out, int out_size, void* d_ws, size_t ws_size,
                              hipStream_t stream) {
  const float* x     = (const float*)d_in[0];
  const float* outp  = (const float*)d_in[1];
  const float* wnorm = (const float*)d_in[2];
  const float* ppre  = (const float*)d_in[3];
  const float* ppost = (const float*)d_in[4];
  const float* pres  = (const float*)d_in[5];
  const float* bpre  = (const float*)d_in[6];
  const float* bpost = (const float*)d_in[7];
  const float* bres  = (const float*)d_in[8];
  const float* apre  = (const float*)d_in[9];
  const float* apost = (const float*)d_in[10];
  const float* ares  = (const float*)d_in[11];
  const int*   aidx  = (const int*)d_in[12];

  float* agg = (float*)d_out;
  float* big = (float*)d_out + (size_t)TOKS * CCH;

  if (ws_size >= WS_NEED) {
    unsigned short* phiT = (unsigned short*)d_ws;
    float* gates = (float*)((char*)d_ws + GATES_OFF);
    hipLaunchKernelGGL(prep_phiT, dim3(128), dim3(256), 0, stream,
                       ppre, ppost, pres, phiT);
    hipLaunchKernelGGL(logits_gates, dim3(256), dim3(512), 0, stream,
                       x, wnorm, phiT, bpre, bpost, bres, apre, apost, ares, aidx, gates);
    hipLaunchKernelGGL(out_pass, dim3(4096), dim3(256), 0, stream, x, outp, gates, agg, big);
  } else {
    hipLaunchKernelGGL(lora_fused, dim3(2048), dim3(256), 0, stream,
                       x, outp, wnorm, ppre, ppost, pres,
                       bpre, bpost, bres, apre, apost, ares, aidx, agg, big);
  }
}

// Round 19
// 106.241 us; speedup vs baseline: 1.0501x; 1.0001x over previous
//
#include <hip/hip_runtime.h>

#define EPS 1e-5f
#define TOKS 4096
#define NCF 8192
#define CCH 2048

#define PHI_BYTES ((size_t)8 * 32 * 8192 * 2)            // 4 MB bf16 phiT (no w fold)
#define GATES_OFF PHI_BYTES                              // float[4096][32] = 512 KB
#define WS_NEED   (GATES_OFF + (size_t)TOKS * 32 * 4)

typedef __attribute__((ext_vector_type(8))) short bf16x8;
typedef __attribute__((ext_vector_type(4))) float f32x4;

__device__ __forceinline__ unsigned short f2bf(float f) {
  unsigned int u = __float_as_uint(f);
  u += 0x7FFFu + ((u >> 16) & 1u);
  return (unsigned short)(u >> 16);
}
__device__ __forceinline__ float bf2f(unsigned short s) {
  return __uint_as_float(((unsigned int)s) << 16);
}
__device__ __forceinline__ unsigned int pack2(float a, float b) {
  return (unsigned int)f2bf(a) | ((unsigned int)f2bf(b) << 16);
}

// ---------------- K0 v2: COALESCED transpose phi -> phiT (bf16, [A][32][8192]) [r15-proven] -------
// rows 0-3 = pre cols, 4-7 = post cols, 8-23 = res cols, 24-31 = zero.
__global__ __launch_bounds__(256)
void prep_phiT(const float* __restrict__ pre, const float* __restrict__ post,
               const float* __restrict__ res, unsigned short* __restrict__ phiT) {
  const int gid = blockIdx.x * 256 + threadIdx.x;    // 8 * 4096 threads
  const int a = gid >> 12;
  const int e0 = (gid & 4095) * 2;

  const float4 p0 = *(const float4*)(pre + ((size_t)a * NCF + e0) * 4);
  const float4 p1 = *(const float4*)(pre + ((size_t)a * NCF + e0) * 4 + 4);
  const float4 q0 = *(const float4*)(post + ((size_t)a * NCF + e0) * 4);
  const float4 q1 = *(const float4*)(post + ((size_t)a * NCF + e0) * 4 + 4);
  float r0[16], r1[16];
  #pragma unroll
  for (int j = 0; j < 4; ++j) {
    const float4 v = *(const float4*)(res + ((size_t)a * NCF + e0) * 16 + j * 4);
    r0[j*4+0] = v.x; r0[j*4+1] = v.y; r0[j*4+2] = v.z; r0[j*4+3] = v.w;
  }
  #pragma unroll
  for (int j = 0; j < 4; ++j) {
    const float4 v = *(const float4*)(res + ((size_t)a * NCF + e0) * 16 + 16 + j * 4);
    r1[j*4+0] = v.x; r1[j*4+1] = v.y; r1[j*4+2] = v.z; r1[j*4+3] = v.w;
  }

  unsigned short* base = phiT + (size_t)a * 32 * NCF + e0;
  const float pr0[4] = { p0.x, p0.y, p0.z, p0.w };
  const float pr1[4] = { p1.x, p1.y, p1.z, p1.w };
  const float po0[4] = { q0.x, q0.y, q0.z, q0.w };
  const float po1[4] = { q1.x, q1.y, q1.z, q1.w };
  #pragma unroll
  for (int r = 0; r < 4; ++r)
    *(unsigned int*)(base + (size_t)r * NCF) = pack2(pr0[r], pr1[r]);
  #pragma unroll
  for (int r = 0; r < 4; ++r)
    *(unsigned int*)(base + (size_t)(4 + r) * NCF) = pack2(po0[r], po1[r]);
  #pragma unroll
  for (int r = 0; r < 16; ++r)
    *(unsigned int*)(base + (size_t)(8 + r) * NCF) = pack2(r0[r], r1[r]);
  #pragma unroll
  for (int r = 24; r < 32; ++r)
    *(unsigned int*)(base + (size_t)r * NCF) = 0u;
}

// ---------------- K1: r6 skeleton + depth-2 register load pipeline ----------------
// 512 threads = 8 waves; wave w owns K-slice [w*1024, (w+1)*1024), 4 chunks of 256.
// xa/xb hold chunks t and t+1 (32 float4 in flight per lane); prefetch t+2 into consumed buf.
// __launch_bounds__(512,1): VGPR cap 256 -> live set ~180 fits, no spill (r12's failure was the 128 cap).
__global__ __launch_bounds__(512, 1)
void logits_gates(const float* __restrict__ x,
                  const float* __restrict__ wnorm,
                  const unsigned short* __restrict__ phiT,
                  const float* __restrict__ b_pre, const float* __restrict__ b_post,
                  const float* __restrict__ b_res,
                  const float* __restrict__ a_pre, const float* __restrict__ a_post,
                  const float* __restrict__ a_res,
                  const int* __restrict__ aidx_arr,
                  float* __restrict__ gates) {
  __shared__ unsigned short xs[8][16 * 264];   // per-wave bf16 tile [16 tok][256 feat], row pad 264
  __shared__ float logits_s[8][16][32];
  __shared__ float ssq_s[8][16];

  const int tid = threadIdx.x;
  const int wave = tid >> 6, lane = tid & 63;
  const int tok0 = blockIdx.x * 16;
  const int aidx = aidx_arr[tok0 >> 10];
  const int kbase = wave * 1024;

  const float* xbase = x + (size_t)tok0 * NCF + kbase + lane * 4;
  const float* wbase = wnorm + (size_t)aidx * NCF + kbase + lane * 4;
  const unsigned short* pBbase =
      phiT + ((size_t)aidx * 32 + (lane & 15)) * NCF + kbase + (lane >> 4) * 8;

  f32x4 acc0 = {0.f, 0.f, 0.f, 0.f};
  f32x4 acc1 = {0.f, 0.f, 0.f, 0.f};
  float ssq[16];
  #pragma unroll
  for (int r = 0; r < 16; ++r) ssq[r] = 0.f;

  float4 xa[16], xb[16];
  #pragma unroll
  for (int r = 0; r < 16; ++r) xa[r] = *(const float4*)(xbase + (size_t)r * NCF);
  #pragma unroll
  for (int r = 0; r < 16; ++r) xb[r] = *(const float4*)(xbase + (size_t)r * NCF + 256);

  #pragma unroll
  for (int t = 0; t < 4; ++t) {
    const float4 wv = *(const float4*)(wbase + t * 256);
    // stage current chunk (xa if t even, xb if t odd); prefetch chunk t+2 into it
    #pragma unroll
    for (int r = 0; r < 16; ++r) {
      const float4 xv = (t & 1) ? xb[r] : xa[r];
      ssq[r] += xv.x * xv.x + xv.y * xv.y + xv.z * xv.z + xv.w * xv.w;
      ushort4 u = make_ushort4(f2bf(xv.x * wv.x), f2bf(xv.y * wv.y),
                               f2bf(xv.z * wv.z), f2bf(xv.w * wv.w));
      *(ushort4*)&xs[wave][r * 264 + lane * 4] = u;
      if (t < 2) {
        const float4 nv = *(const float4*)(xbase + (size_t)r * NCF + (t + 2) * 256);
        if (t & 1) xb[r] = nv; else xa[r] = nv;
      }
    }
    const unsigned short* pB = pBbase + t * 256;
    #pragma unroll
    for (int s = 0; s < 8; ++s) {
      bf16x8 a = *(const bf16x8*)&xs[wave][(lane & 15) * 264 + s * 32 + (lane >> 4) * 8];
      bf16x8 b0 = *(const bf16x8*)(pB + s * 32);
      bf16x8 b1 = *(const bf16x8*)(pB + 16 * NCF + s * 32);
      acc0 = __builtin_amdgcn_mfma_f32_16x16x32_bf16(a, b0, acc0, 0, 0, 0);
      acc1 = __builtin_amdgcn_mfma_f32_16x16x32_bf16(a, b1, acc1, 0, 0, 0);
    }
  }

  // ssq reduce across 64 lanes
  #pragma unroll
  for (int r = 0; r < 16; ++r) {
    float v = ssq[r];
    #pragma unroll
    for (int m = 1; m <= 32; m <<= 1) v += __shfl_xor(v, m, 64);
    if (lane == 0) ssq_s[wave][r] = v;
  }
  // C frags -> LDS: D[m=tok][n=col], m=(lane>>4)*4+i, n=lane&15
  #pragma unroll
  for (int i = 0; i < 4; ++i) {
    logits_s[wave][(lane >> 4) * 4 + i][lane & 15] = acc0[i];
    logits_s[wave][(lane >> 4) * 4 + i][16 + (lane & 15)] = acc1[i];
  }
  __syncthreads();

  if (tid < 256) {
    // per-thread: tok = tid>>4 (0..15), cl = tid&15
    const int tok = tid >> 4, cl = tid & 15;
    float L0 = 0.f, L16 = 0.f, ssqt = 0.f;
    #pragma unroll
    for (int w = 0; w < 8; ++w) {
      L0 += logits_s[w][tok][cl];
      L16 += logits_s[w][tok][16 + cl];
      ssqt += ssq_s[w][tok];
    }
    const float invr = rsqrtf(ssqt * (1.f / NCF) + EPS);

    float* g = gates + (size_t)(tok0 + tok) * 32;
    if (cl < 4) {
      const float zp = a_pre[aidx] * L0 * invr + b_pre[(size_t)aidx * 4 + cl];
      g[cl] = 1.f / (1.f + __expf(-zp));
    } else if (cl < 8) {
      const float zq = a_post[aidx] * L0 * invr + b_post[(size_t)aidx * 4 + (cl - 4)];
      g[cl] = 2.f / (1.f + __expf(-zq));
    }
    // gather res logits: res[cl] = col 8+cl
    const float resv = __shfl_xor((cl & 8) ? L0 : L16, 8, 64);
    const float tl = a_res[aidx] * resv * invr + b_res[(size_t)aidx * 16 + cl];
    float m = __expf(tl);
    #pragma unroll
    for (int it = 0; it < 20; ++it) {
      float rs = m;
      rs += __shfl_xor(rs, 1, 64);
      rs += __shfl_xor(rs, 2, 64);
      m *= __builtin_amdgcn_rcpf(rs);
      float cs = m;
      cs += __shfl_xor(cs, 4, 64);
      cs += __shfl_xor(cs, 8, 64);
      m *= __builtin_amdgcn_rcpf(cs);
    }
    g[8 + cl] = m;
  }
}

// ---------------- K3: streaming output pass  [r6-proven verbatim] ----------------
__global__ __launch_bounds__(256)
void out_pass(const float* __restrict__ x, const float* __restrict__ outp,
              const float* __restrict__ gates,
              float* __restrict__ agg, float* __restrict__ big) {
  const int tok = blockIdx.x;
  const int tid = threadIdx.x;
  const float* g = gates + (size_t)tok * 32;
  float hp[4], hq[4], M[16];
  #pragma unroll
  for (int i = 0; i < 4; ++i) { hp[i] = g[i]; hq[i] = g[4 + i]; }
  #pragma unroll
  for (int i = 0; i < 16; ++i) M[i] = g[8 + i];

  const float* xrow = x + (size_t)tok * NCF;
  const float* orow = outp + (size_t)tok * CCH;
  float* arow = agg + (size_t)tok * CCH;
  float* brow = big + (size_t)tok * NCF;

  #pragma unroll
  for (int rep = 0; rep < 2; ++rep) {
    const int c = rep * 1024 + tid * 4;
    float4 xv[4];
    #pragma unroll
    for (int j = 0; j < 4; ++j) xv[j] = *(const float4*)(xrow + j * CCH + c);
    const float4 ov = *(const float4*)(orow + c);

    f32x4 ag;
    ag.x = hp[0]*xv[0].x + hp[1]*xv[1].x + hp[2]*xv[2].x + hp[3]*xv[3].x;
    ag.y = hp[0]*xv[0].y + hp[1]*xv[1].y + hp[2]*xv[2].y + hp[3]*xv[3].y;
    ag.z = hp[0]*xv[0].z + hp[1]*xv[1].z + hp[2]*xv[2].z + hp[3]*xv[3].z;
    ag.w = hp[0]*xv[0].w + hp[1]*xv[1].w + hp[2]*xv[2].w + hp[3]*xv[3].w;
    __builtin_nontemporal_store(ag, (f32x4*)(arow + c));

    #pragma unroll
    for (int i = 0; i < 4; ++i) {
      const float m0 = M[i*4+0], m1 = M[i*4+1], m2 = M[i*4+2], m3 = M[i*4+3];
      f32x4 o;
      o.x = m0*xv[0].x + m1*xv[1].x + m2*xv[2].x + m3*xv[3].x + hq[i]*ov.x;
      o.y = m0*xv[0].y + m1*xv[1].y + m2*xv[2].y + m3*xv[3].y + hq[i]*ov.y;
      o.z = m0*xv[0].z + m1*xv[1].z + m2*xv[2].z + m3*xv[3].z + hq[i]*ov.z;
      o.w = m0*xv[0].w + m1*xv[1].w + m2*xv[2].w + m3*xv[3].w + hq[i]*ov.w;
      __builtin_nontemporal_store(o, (f32x4*)(brow + i * CCH + c));
    }
  }
}

// ---------------- fallback: round-1 fused kernel (used if ws too small) ----------------
__global__ __launch_bounds__(256, 4)
void lora_fused(const float* __restrict__ x, const float* __restrict__ outp,
                const float* __restrict__ wnorm, const float* __restrict__ phi_pre,
                const float* __restrict__ phi_post, const float* __restrict__ phi_res,
                const float* __restrict__ b_pre, const float* __restrict__ b_post,
                const float* __restrict__ b_res, const float* __restrict__ a_pre,
                const float* __restrict__ a_post, const float* __restrict__ a_res,
                const int* __restrict__ aidx_arr, float* __restrict__ agg_out,
                float* __restrict__ big_out) {
  __shared__ unsigned short xsb[2][NCF];
  __shared__ float scratch[4][52];
  __shared__ float red[52];
  __shared__ float Hpre[2][4], Hpost[2][4], Msm[2][16];
  const int tid = threadIdx.x;
  const int tok0 = blockIdx.x * 2;
  const int aidx = aidx_arr[tok0 >> 10];
  const float* xr0 = x + (size_t)tok0 * NCF;
  const float* xr1 = xr0 + NCF;
  const float* wr = wnorm + (size_t)aidx * NCF;
  const float* pp = phi_pre + (size_t)aidx * NCF * 4;
  const float* pq = phi_post + (size_t)aidx * NCF * 4;
  const float* pr = phi_res + (size_t)aidx * NCF * 16;
  float acc[50];
  #pragma unroll
  for (int i = 0; i < 50; ++i) acc[i] = 0.f;
  for (int k = 0; k < 8; ++k) {
    const int f0 = (k * 256 + tid) * 4;
    const float4 w4 = *(const float4*)(wr + f0);
    const float4 xa = *(const float4*)(xr0 + f0);
    const float4 xb = *(const float4*)(xr1 + f0);
    acc[0] += xa.x*xa.x + xa.y*xa.y + xa.z*xa.z + xa.w*xa.w;
    acc[25] += xb.x*xb.x + xb.y*xb.y + xb.z*xb.z + xb.w*xb.w;
    float xw0[4] = { xa.x*w4.x, xa.y*w4.y, xa.z*w4.z, xa.w*w4.w };
    float xw1[4] = { xb.x*w4.x, xb.y*w4.y, xb.z*w4.z, xb.w*w4.w };
    *(ushort4*)&xsb[0][f0] = make_ushort4(f2bf(xa.x), f2bf(xa.y), f2bf(xa.z), f2bf(xa.w));
    *(ushort4*)&xsb[1][f0] = make_ushort4(f2bf(xb.x), f2bf(xb.y), f2bf(xb.z), f2bf(xb.w));
    #pragma unroll
    for (int d = 0; d < 4; ++d) {
      const int f = f0 + d;
      const float a0 = xw0[d], a1 = xw1[d];
      float col[24];
      const float4 P = *(const float4*)(pp + ((size_t)f << 2));
      const float4 Q = *(const float4*)(pq + ((size_t)f << 2));
      const float4 R0 = *(const float4*)(pr + ((size_t)f << 4));
      const float4 R1 = *(const float4*)(pr + ((size_t)f << 4) + 4);
      const float4 R2 = *(const float4*)(pr + ((size_t)f << 4) + 8);
      const float4 R3 = *(const float4*)(pr + ((size_t)f << 4) + 12);
      col[0]=P.x; col[1]=P.y; col[2]=P.z; col[3]=P.w;
      col[4]=Q.x; col[5]=Q.y; col[6]=Q.z; col[7]=Q.w;
      col[8]=R0.x; col[9]=R0.y; col[10]=R0.z; col[11]=R0.w;
      col[12]=R1.x; col[13]=R1.y; col[14]=R1.z; col[15]=R1.w;
      col[16]=R2.x; col[17]=R2.y; col[18]=R2.z; col[19]=R2.w;
      col[20]=R3.x; col[21]=R3.y; col[22]=R3.z; col[23]=R3.w;
      #pragma unroll
      for (int c = 0; c < 24; ++c) { acc[1 + c] += a0 * col[c]; acc[26 + c] += a1 * col[c]; }
    }
  }
  #pragma unroll
  for (int m = 1; m <= 32; m <<= 1) {
    #pragma unroll
    for (int v = 0; v < 50; ++v) acc[v] += __shfl_xor(acc[v], m, 64);
  }
  const int wave = tid >> 6, lane = tid & 63;
  if (lane == 0) {
    #pragma unroll
    for (int v = 0; v < 50; ++v) scratch[wave][v] = acc[v];
  }
  __syncthreads();
  if (tid < 50) red[tid] = scratch[0][tid] + scratch[1][tid] + scratch[2][tid] + scratch[3][tid];
  __syncthreads();
  if (tid < 32) {
    const int t = tid >> 4, l = tid & 15;
    const float invr = rsqrtf(red[t * 25] * (1.f / NCF) + EPS);
    const float tl = a_res[aidx] * red[t * 25 + 1 + 8 + l] * invr + b_res[(size_t)aidx * 16 + l];
    float m = __expf(tl);
    #pragma unroll
    for (int it = 0; it < 20; ++it) {
      float rs = m; rs += __shfl_xor(rs, 1, 64); rs += __shfl_xor(rs, 2, 64);
      m *= __builtin_amdgcn_rcpf(rs);
      float cs = m; cs += __shfl_xor(cs, 4, 64); cs += __shfl_xor(cs, 8, 64);
      m *= __builtin_amdgcn_rcpf(cs);
    }
    Msm[t][l] = m;
  } else if (tid < 40) {
    const int q = tid - 32, t = q >> 2, n = q & 3;
    const float invr = rsqrtf(red[t * 25] * (1.f / NCF) + EPS);
    const float zp = a_pre[aidx] * red[t * 25 + 1 + n] * invr + b_pre[(size_t)aidx * 4 + n];
    const float zq = a_post[aidx] * red[t * 25 + 1 + 4 + n] * invr + b_post[(size_t)aidx * 4 + n];
    Hpre[t][n] = 1.f / (1.f + __expf(-zp));
    Hpost[t][n] = 2.f / (1.f + __expf(-zq));
  }
  __syncthreads();
  #pragma unroll
  for (int t = 0; t < 2; ++t) {
    const int tok = tok0 + t;
    const float* orow = outp + (size_t)tok * CCH;
    float* arow = agg_out + (size_t)tok * CCH;
    float* brow = big_out + (size_t)tok * 4 * CCH;
    const float hp0 = Hpre[t][0], hp1 = Hpre[t][1], hp2 = Hpre[t][2], hp3 = Hpre[t][3];
    float Mr[16];
    #pragma unroll
    for (int i = 0; i < 16; ++i) Mr[i] = Msm[t][i];
    const float hq[4] = { Hpost[t][0], Hpost[t][1], Hpost[t][2], Hpost[t][3] };
    #pragma unroll
    for (int w = 0; w < 2; ++w) {
      const int c0 = (w * 256 + tid) * 4;
      float4 xv[4];
      #pragma unroll
      for (int n = 0; n < 4; ++n) {
        const ushort4 u = *(const ushort4*)&xsb[t][n * CCH + c0];
        xv[n] = make_float4(bf2f(u.x), bf2f(u.y), bf2f(u.z), bf2f(u.w));
      }
      const float4 ov = *(const float4*)(orow + c0);
      float4 ag;
      ag.x = hp0*xv[0].x + hp1*xv[1].x + hp2*xv[2].x + hp3*xv[3].x;
      ag.y = hp0*xv[0].y + hp1*xv[1].y + hp2*xv[2].y + hp3*xv[3].y;
      ag.z = hp0*xv[0].z + hp1*xv[1].z + hp2*xv[2].z + hp3*xv[3].z;
      ag.w = hp0*xv[0].w + hp1*xv[1].w + hp2*xv[2].w + hp3*xv[3].w;
      *(float4*)(arow + c0) = ag;
      #pragma unroll
      for (int i = 0; i < 4; ++i) {
        const float m0 = Mr[i*4+0], m1 = Mr[i*4+1], m2 = Mr[i*4+2], m3 = Mr[i*4+3];
        float4 o;
        o.x = m0*xv[0].x + m1*xv[1].x + m2*xv[2].x + m3*xv[3].x + hq[i]*ov.x;
        o.y = m0*xv[0].y + m1*xv[1].y + m2*xv[2].y + m3*xv[3].y + hq[i]*ov.y;
        o.z = m0*xv[0].z + m1*xv[1].z + m2*xv[2].z + m3*xv[3].z + hq[i]*ov.z;
        o.w = m0*xv[0].w + m1*xv[1].w + m2*xv[2].w + m3*xv[3].w + hq[i]*ov.w;
        *(float4*)(brow + (size_t)i * CCH + c0) = o;
      }
    }
  }
}

extern "C" void kernel_launch(void* const* d_in, const int* in_sizes, int n_in,
                              void* d_out, int out_size, void* d_ws, size_t ws_size,
                              hipStream_t stream) {
  const float* x     = (const float*)d_in[0];
  const float* outp  = (const float*)d_in[1];
  const float* wnorm = (const float*)d_in[2];
  const float* ppre  = (const float*)d_in[3];
  const float* ppost = (const float*)d_in[4];
  const float* pres  = (const float*)d_in[5];
  const float* bpre  = (const float*)d_in[6];
  const float* bpost = (const float*)d_in[7];
  const float* bres  = (const float*)d_in[8];
  const float* apre  = (const float*)d_in[9];
  const float* apost = (const float*)d_in[10];
  const float* ares  = (const float*)d_in[11];
  const int*   aidx  = (const int*)d_in[12];

  float* agg = (float*)d_out;
  float* big = (float*)d_out + (size_t)TOKS * CCH;

  if (ws_size >= WS_NEED) {
    unsigned short* phiT = (unsigned short*)d_ws;
    float* gates = (float*)((char*)d_ws + GATES_OFF);
    hipLaunchKernelGGL(prep_phiT, dim3(128), dim3(256), 0, stream,
                       ppre, ppost, pres, phiT);
    hipLaunchKernelGGL(logits_gates, dim3(256), dim3(512), 0, stream,
                       x, wnorm, phiT, bpre, bpost, bres, apre, apost, ares, aidx, gates);
    hipLaunchKernelGGL(out_pass, dim3(4096), dim3(256), 0, stream, x, outp, gates, agg, big);
  } else {
    hipLaunchKernelGGL(lora_fused, dim3(2048), dim3(256), 0, stream,
                       x, outp, wnorm, ppre, ppost, pres,
                       bpre, bpost, bres, apre, apost, ares, aidx, agg, big);
  }
}

// Round 20
// 103.242 us; speedup vs baseline: 1.0806x; 1.0291x over previous
//
#include <hip/hip_runtime.h>

#define EPS 1e-5f
#define TOKS 4096
#define NCF 8192
#define CCH 2048

#define PHI_BYTES ((size_t)8 * 32 * 8192 * 2)            // 4 MB bf16 phiT (no w fold)
#define GATES_OFF PHI_BYTES                              // float[4096][32] = 512 KB
#define WS_NEED   (GATES_OFF + (size_t)TOKS * 32 * 4)

typedef __attribute__((ext_vector_type(8))) short bf16x8;
typedef __attribute__((ext_vector_type(4))) float f32x4;

__device__ __forceinline__ unsigned short f2bf(float f) {
  unsigned int u = __float_as_uint(f);
  u += 0x7FFFu + ((u >> 16) & 1u);
  return (unsigned short)(u >> 16);
}
__device__ __forceinline__ float bf2f(unsigned short s) {
  return __uint_as_float(((unsigned int)s) << 16);
}
__device__ __forceinline__ unsigned int pack2(float a, float b) {
  return (unsigned int)f2bf(a) | ((unsigned int)f2bf(b) << 16);
}

// ---------------- K0 v2: COALESCED transpose phi -> phiT (bf16, [A][32][8192]) [r15-proven] -------
// rows 0-3 = pre cols, 4-7 = post cols, 8-23 = res cols, 24-31 = zero.
__global__ __launch_bounds__(256)
void prep_phiT(const float* __restrict__ pre, const float* __restrict__ post,
               const float* __restrict__ res, unsigned short* __restrict__ phiT) {
  const int gid = blockIdx.x * 256 + threadIdx.x;    // 8 * 4096 threads
  const int a = gid >> 12;
  const int e0 = (gid & 4095) * 2;

  const float4 p0 = *(const float4*)(pre + ((size_t)a * NCF + e0) * 4);
  const float4 p1 = *(const float4*)(pre + ((size_t)a * NCF + e0) * 4 + 4);
  const float4 q0 = *(const float4*)(post + ((size_t)a * NCF + e0) * 4);
  const float4 q1 = *(const float4*)(post + ((size_t)a * NCF + e0) * 4 + 4);
  float r0[16], r1[16];
  #pragma unroll
  for (int j = 0; j < 4; ++j) {
    const float4 v = *(const float4*)(res + ((size_t)a * NCF + e0) * 16 + j * 4);
    r0[j*4+0] = v.x; r0[j*4+1] = v.y; r0[j*4+2] = v.z; r0[j*4+3] = v.w;
  }
  #pragma unroll
  for (int j = 0; j < 4; ++j) {
    const float4 v = *(const float4*)(res + ((size_t)a * NCF + e0) * 16 + 16 + j * 4);
    r1[j*4+0] = v.x; r1[j*4+1] = v.y; r1[j*4+2] = v.z; r1[j*4+3] = v.w;
  }

  unsigned short* base = phiT + (size_t)a * 32 * NCF + e0;
  const float pr0[4] = { p0.x, p0.y, p0.z, p0.w };
  const float pr1[4] = { p1.x, p1.y, p1.z, p1.w };
  const float po0[4] = { q0.x, q0.y, q0.z, q0.w };
  const float po1[4] = { q1.x, q1.y, q1.z, q1.w };
  #pragma unroll
  for (int r = 0; r < 4; ++r)
    *(unsigned int*)(base + (size_t)r * NCF) = pack2(pr0[r], pr1[r]);
  #pragma unroll
  for (int r = 0; r < 4; ++r)
    *(unsigned int*)(base + (size_t)(4 + r) * NCF) = pack2(po0[r], po1[r]);
  #pragma unroll
  for (int r = 0; r < 16; ++r)
    *(unsigned int*)(base + (size_t)(8 + r) * NCF) = pack2(r0[r], r1[r]);
  #pragma unroll
  for (int r = 24; r < 32; ++r)
    *(unsigned int*)(base + (size_t)r * NCF) = 0u;
}

// ---------------- K1: r15 K-loop verbatim; reduction via 2 KB LDS atomicAdd ----------------
// LDS: 67.6 KB (xs) + 2 KB (logAcc) + 64 B (ssqAcc) = 69.7 KB -> 2 blocks/CU = 16 waves/CU
// (r15 had 84.5 KB -> 1 block/CU; this doubles in-flight x loads with no register change).
// atomicAdd accumulation [r11-proven]; direct-read gates mapping [r13-proven].
__global__ __launch_bounds__(512, 1)
void logits_gates(const float* __restrict__ x,
                  const float* __restrict__ wnorm,
                  const unsigned short* __restrict__ phiT,
                  const float* __restrict__ b_pre, const float* __restrict__ b_post,
                  const float* __restrict__ b_res,
                  const float* __restrict__ a_pre, const float* __restrict__ a_post,
                  const float* __restrict__ a_res,
                  const int* __restrict__ aidx_arr,
                  float* __restrict__ gates) {
  __shared__ unsigned short xs[8][16 * 264];   // per-wave bf16 tile [16 tok][256 feat], row pad 264
  __shared__ float logAcc[16][32];
  __shared__ float ssqAcc[16];

  const int tid = threadIdx.x;
  const int wave = tid >> 6, lane = tid & 63;
  const int tok0 = blockIdx.x * 16;
  const int aidx = aidx_arr[tok0 >> 10];
  const int kbase = wave * 1024;

  ((float*)logAcc)[tid] = 0.f;                 // 512 threads cover 16x32 exactly
  if (tid < 16) ssqAcc[tid] = 0.f;
  __syncthreads();

  const float* xbase = x + (size_t)tok0 * NCF + kbase + lane * 4;
  const float* wbase = wnorm + (size_t)aidx * NCF + kbase + lane * 4;
  const unsigned short* pBbase =
      phiT + ((size_t)aidx * 32 + (lane & 15)) * NCF + kbase + (lane >> 4) * 8;

  f32x4 acc0 = {0.f, 0.f, 0.f, 0.f};
  f32x4 acc1 = {0.f, 0.f, 0.f, 0.f};
  float ssq[16];
  #pragma unroll
  for (int r = 0; r < 16; ++r) ssq[r] = 0.f;

  float4 xr[16];
  #pragma unroll
  for (int r = 0; r < 16; ++r) xr[r] = *(const float4*)(xbase + (size_t)r * NCF);

  for (int t = 0; t < 4; ++t) {
    const float4 wv = *(const float4*)(wbase + t * 256);
    // stage: ssq + bf16(w*x) -> LDS (wave-private, no barrier needed)
    #pragma unroll
    for (int r = 0; r < 16; ++r) {
      const float4 xv = xr[r];
      ssq[r] += xv.x * xv.x + xv.y * xv.y + xv.z * xv.z + xv.w * xv.w;
      ushort4 u = make_ushort4(f2bf(xv.x * wv.x), f2bf(xv.y * wv.y),
                               f2bf(xv.z * wv.z), f2bf(xv.w * wv.w));
      *(ushort4*)&xs[wave][r * 264 + lane * 4] = u;
    }
    if (t < 3) {
      #pragma unroll
      for (int r = 0; r < 16; ++r)
        xr[r] = *(const float4*)(xbase + (size_t)r * NCF + (t + 1) * 256);
    }
    const unsigned short* pB = pBbase + t * 256;
    #pragma unroll
    for (int s = 0; s < 8; ++s) {
      bf16x8 a = *(const bf16x8*)&xs[wave][(lane & 15) * 264 + s * 32 + (lane >> 4) * 8];
      bf16x8 b0 = *(const bf16x8*)(pB + s * 32);
      bf16x8 b1 = *(const bf16x8*)(pB + 16 * NCF + s * 32);
      acc0 = __builtin_amdgcn_mfma_f32_16x16x32_bf16(a, b0, acc0, 0, 0, 0);
      acc1 = __builtin_amdgcn_mfma_f32_16x16x32_bf16(a, b1, acc1, 0, 0, 0);
    }
  }

  // ssq: shuffle-reduce then one atomic per (wave,row)
  #pragma unroll
  for (int r = 0; r < 16; ++r) {
    float v = ssq[r];
    #pragma unroll
    for (int m = 1; m <= 32; m <<= 1) v += __shfl_xor(v, m, 64);
    if (lane == 0) atomicAdd(&ssqAcc[r], v);
  }
  // C frags: D row=(lane>>4)*4+i, col=lane&15  [r6/r11-proven mapping]
  #pragma unroll
  for (int i = 0; i < 4; ++i) {
    atomicAdd(&logAcc[(lane >> 4) * 4 + i][lane & 15], acc0[i]);
    atomicAdd(&logAcc[(lane >> 4) * 4 + i][16 + (lane & 15)], acc1[i]);
  }
  __syncthreads();

  if (tid < 256) {
    // per-thread: tok = tid>>4 (0..15), cl = tid&15  [r13-proven direct-read mapping]
    const int tok = tid >> 4, cl = tid & 15;
    const float Lg   = logAcc[tok][cl];          // pre: cols 0-3, post: cols 4-7
    const float Lres = logAcc[tok][8 + cl];      // res logit l=cl lives at col 8+cl
    const float ssqt = ssqAcc[tok];
    const float invr = rsqrtf(ssqt * (1.f / NCF) + EPS);

    float* g = gates + (size_t)(tok0 + tok) * 32;
    if (cl < 4) {
      const float zp = a_pre[aidx] * Lg * invr + b_pre[(size_t)aidx * 4 + cl];
      g[cl] = 1.f / (1.f + __expf(-zp));
    } else if (cl < 8) {
      const float zq = a_post[aidx] * Lg * invr + b_post[(size_t)aidx * 4 + (cl - 4)];
      g[cl] = 2.f / (1.f + __expf(-zq));
    }
    const float tl = a_res[aidx] * Lres * invr + b_res[(size_t)aidx * 16 + cl];
    float m = __expf(tl);
    #pragma unroll
    for (int it = 0; it < 20; ++it) {
      float rs = m;
      rs += __shfl_xor(rs, 1, 64);
      rs += __shfl_xor(rs, 2, 64);
      m *= __builtin_amdgcn_rcpf(rs);
      float cs = m;
      cs += __shfl_xor(cs, 4, 64);
      cs += __shfl_xor(cs, 8, 64);
      m *= __builtin_amdgcn_rcpf(cs);
    }
    g[8 + cl] = m;
  }
}

// ---------------- K3: streaming output pass  [r6-proven verbatim] ----------------
__global__ __launch_bounds__(256)
void out_pass(const float* __restrict__ x, const float* __restrict__ outp,
              const float* __restrict__ gates,
              float* __restrict__ agg, float* __restrict__ big) {
  const int tok = blockIdx.x;
  const int tid = threadIdx.x;
  const float* g = gates + (size_t)tok * 32;
  float hp[4], hq[4], M[16];
  #pragma unroll
  for (int i = 0; i < 4; ++i) { hp[i] = g[i]; hq[i] = g[4 + i]; }
  #pragma unroll
  for (int i = 0; i < 16; ++i) M[i] = g[8 + i];

  const float* xrow = x + (size_t)tok * NCF;
  const float* orow = outp + (size_t)tok * CCH;
  float* arow = agg + (size_t)tok * CCH;
  float* brow = big + (size_t)tok * NCF;

  #pragma unroll
  for (int rep = 0; rep < 2; ++rep) {
    const int c = rep * 1024 + tid * 4;
    float4 xv[4];
    #pragma unroll
    for (int j = 0; j < 4; ++j) xv[j] = *(const float4*)(xrow + j * CCH + c);
    const float4 ov = *(const float4*)(orow + c);

    f32x4 ag;
    ag.x = hp[0]*xv[0].x + hp[1]*xv[1].x + hp[2]*xv[2].x + hp[3]*xv[3].x;
    ag.y = hp[0]*xv[0].y + hp[1]*xv[1].y + hp[2]*xv[2].y + hp[3]*xv[3].y;
    ag.z = hp[0]*xv[0].z + hp[1]*xv[1].z + hp[2]*xv[2].z + hp[3]*xv[3].z;
    ag.w = hp[0]*xv[0].w + hp[1]*xv[1].w + hp[2]*xv[2].w + hp[3]*xv[3].w;
    __builtin_nontemporal_store(ag, (f32x4*)(arow + c));

    #pragma unroll
    for (int i = 0; i < 4; ++i) {
      const float m0 = M[i*4+0], m1 = M[i*4+1], m2 = M[i*4+2], m3 = M[i*4+3];
      f32x4 o;
      o.x = m0*xv[0].x + m1*xv[1].x + m2*xv[2].x + m3*xv[3].x + hq[i]*ov.x;
      o.y = m0*xv[0].y + m1*xv[1].y + m2*xv[2].y + m3*xv[3].y + hq[i]*ov.y;
      o.z = m0*xv[0].z + m1*xv[1].z + m2*xv[2].z + m3*xv[3].z + hq[i]*ov.z;
      o.w = m0*xv[0].w + m1*xv[1].w + m2*xv[2].w + m3*xv[3].w + hq[i]*ov.w;
      __builtin_nontemporal_store(o, (f32x4*)(brow + i * CCH + c));
    }
  }
}

// ---------------- fallback: round-1 fused kernel (used if ws too small) ----------------
__global__ __launch_bounds__(256, 4)
void lora_fused(const float* __restrict__ x, const float* __restrict__ outp,
                const float* __restrict__ wnorm, const float* __restrict__ phi_pre,
                const float* __restrict__ phi_post, const float* __restrict__ phi_res,
                const float* __restrict__ b_pre, const float* __restrict__ b_post,
                const float* __restrict__ b_res, const float* __restrict__ a_pre,
                const float* __restrict__ a_post, const float* __restrict__ a_res,
                const int* __restrict__ aidx_arr, float* __restrict__ agg_out,
                float* __restrict__ big_out) {
  __shared__ unsigned short xsb[2][NCF];
  __shared__ float scratch[4][52];
  __shared__ float red[52];
  __shared__ float Hpre[2][4], Hpost[2][4], Msm[2][16];
  const int tid = threadIdx.x;
  const int tok0 = blockIdx.x * 2;
  const int aidx = aidx_arr[tok0 >> 10];
  const float* xr0 = x + (size_t)tok0 * NCF;
  const float* xr1 = xr0 + NCF;
  const float* wr = wnorm + (size_t)aidx * NCF;
  const float* pp = phi_pre + (size_t)aidx * NCF * 4;
  const float* pq = phi_post + (size_t)aidx * NCF * 4;
  const float* pr = phi_res + (size_t)aidx * NCF * 16;
  float acc[50];
  #pragma unroll
  for (int i = 0; i < 50; ++i) acc[i] = 0.f;
  for (int k = 0; k < 8; ++k) {
    const int f0 = (k * 256 + tid) * 4;
    const float4 w4 = *(const float4*)(wr + f0);
    const float4 xa = *(const float4*)(xr0 + f0);
    const float4 xb = *(const float4*)(xr1 + f0);
    acc[0] += xa.x*xa.x + xa.y*xa.y + xa.z*xa.z + xa.w*xa.w;
    acc[25] += xb.x*xb.x + xb.y*xb.y + xb.z*xb.z + xb.w*xb.w;
    float xw0[4] = { xa.x*w4.x, xa.y*w4.y, xa.z*w4.z, xa.w*w4.w };
    float xw1[4] = { xb.x*w4.x, xb.y*w4.y, xb.z*w4.z, xb.w*w4.w };
    *(ushort4*)&xsb[0][f0] = make_ushort4(f2bf(xa.x), f2bf(xa.y), f2bf(xa.z), f2bf(xa.w));
    *(ushort4*)&xsb[1][f0] = make_ushort4(f2bf(xb.x), f2bf(xb.y), f2bf(xb.z), f2bf(xb.w));
    #pragma unroll
    for (int d = 0; d < 4; ++d) {
      const int f = f0 + d;
      const float a0 = xw0[d], a1 = xw1[d];
      float col[24];
      const float4 P = *(const float4*)(pp + ((size_t)f << 2));
      const float4 Q = *(const float4*)(pq + ((size_t)f << 2));
      const float4 R0 = *(const float4*)(pr + ((size_t)f << 4));
      const float4 R1 = *(const float4*)(pr + ((size_t)f << 4) + 4);
      const float4 R2 = *(const float4*)(pr + ((size_t)f << 4) + 8);
      const float4 R3 = *(const float4*)(pr + ((size_t)f << 4) + 12);
      col[0]=P.x; col[1]=P.y; col[2]=P.z; col[3]=P.w;
      col[4]=Q.x; col[5]=Q.y; col[6]=Q.z; col[7]=Q.w;
      col[8]=R0.x; col[9]=R0.y; col[10]=R0.z; col[11]=R0.w;
      col[12]=R1.x; col[13]=R1.y; col[14]=R1.z; col[15]=R1.w;
      col[16]=R2.x; col[17]=R2.y; col[18]=R2.z; col[19]=R2.w;
      col[20]=R3.x; col[21]=R3.y; col[22]=R3.z; col[23]=R3.w;
      #pragma unroll
      for (int c = 0; c < 24; ++c) { acc[1 + c] += a0 * col[c]; acc[26 + c] += a1 * col[c]; }
    }
  }
  #pragma unroll
  for (int m = 1; m <= 32; m <<= 1) {
    #pragma unroll
    for (int v = 0; v < 50; ++v) acc[v] += __shfl_xor(acc[v], m, 64);
  }
  const int wave = tid >> 6, lane = tid & 63;
  if (lane == 0) {
    #pragma unroll
    for (int v = 0; v < 50; ++v) scratch[wave][v] = acc[v];
  }
  __syncthreads();
  if (tid < 50) red[tid] = scratch[0][tid] + scratch[1][tid] + scratch[2][tid] + scratch[3][tid];
  __syncthreads();
  if (tid < 32) {
    const int t = tid >> 4, l = tid & 15;
    const float invr = rsqrtf(red[t * 25] * (1.f / NCF) + EPS);
    const float tl = a_res[aidx] * red[t * 25 + 1 + 8 + l] * invr + b_res[(size_t)aidx * 16 + l];
    float m = __expf(tl);
    #pragma unroll
    for (int it = 0; it < 20; ++it) {
      float rs = m; rs += __shfl_xor(rs, 1, 64); rs += __shfl_xor(rs, 2, 64);
      m *= __builtin_amdgcn_rcpf(rs);
      float cs = m; cs += __shfl_xor(cs, 4, 64); cs += __shfl_xor(cs, 8, 64);
      m *= __builtin_amdgcn_rcpf(cs);
    }
    Msm[t][l] = m;
  } else if (tid < 40) {
    const int q = tid - 32, t = q >> 2, n = q & 3;
    const float invr = rsqrtf(red[t * 25] * (1.f / NCF) + EPS);
    const float zp = a_pre[aidx] * red[t * 25 + 1 + n] * invr + b_pre[(size_t)aidx * 4 + n];
    const float zq = a_post[aidx] * red[t * 25 + 1 + 4 + n] * invr + b_post[(size_t)aidx * 4 + n];
    Hpre[t][n] = 1.f / (1.f + __expf(-zp));
    Hpost[t][n] = 2.f / (1.f + __expf(-zq));
  }
  __syncthreads();
  #pragma unroll
  for (int t = 0; t < 2; ++t) {
    const int tok = tok0 + t;
    const float* orow = outp + (size_t)tok * CCH;
    float* arow = agg_out + (size_t)tok * CCH;
    float* brow = big_out + (size_t)tok * 4 * CCH;
    const float hp0 = Hpre[t][0], hp1 = Hpre[t][1], hp2 = Hpre[t][2], hp3 = Hpre[t][3];
    float Mr[16];
    #pragma unroll
    for (int i = 0; i < 16; ++i) Mr[i] = Msm[t][i];
    const float hq[4] = { Hpost[t][0], Hpost[t][1], Hpost[t][2], Hpost[t][3] };
    #pragma unroll
    for (int w = 0; w < 2; ++w) {
      const int c0 = (w * 256 + tid) * 4;
      float4 xv[4];
      #pragma unroll
      for (int n = 0; n < 4; ++n) {
        const ushort4 u = *(const ushort4*)&xsb[t][n * CCH + c0];
        xv[n] = make_float4(bf2f(u.x), bf2f(u.y), bf2f(u.z), bf2f(u.w));
      }
      const float4 ov = *(const float4*)(orow + c0);
      float4 ag;
      ag.x = hp0*xv[0].x + hp1*xv[1].x + hp2*xv[2].x + hp3*xv[3].x;
      ag.y = hp0*xv[0].y + hp1*xv[1].y + hp2*xv[2].y + hp3*xv[3].y;
      ag.z = hp0*xv[0].z + hp1*xv[1].z + hp2*xv[2].z + hp3*xv[3].z;
      ag.w = hp0*xv[0].w + hp1*xv[1].w + hp2*xv[2].w + hp3*xv[3].w;
      *(float4*)(arow + c0) = ag;
      #pragma unroll
      for (int i = 0; i < 4; ++i) {
        const float m0 = Mr[i*4+0], m1 = Mr[i*4+1], m2 = Mr[i*4+2], m3 = Mr[i*4+3];
        float4 o;
        o.x = m0*xv[0].x + m1*xv[1].x + m2*xv[2].x + m3*xv[3].x + hq[i]*ov.x;
        o.y = m0*xv[0].y + m1*xv[1].y + m2*xv[2].y + m3*xv[3].y + hq[i]*ov.y;
        o.z = m0*xv[0].z + m1*xv[1].z + m2*xv[2].z + m3*xv[3].z + hq[i]*ov.z;
        o.w = m0*xv[0].w + m1*xv[1].w + m2*xv[2].w + m3*xv[3].w + hq[i]*ov.w;
        *(float4*)(brow + (size_t)i * CCH + c0) = o;
      }
    }
  }
}

extern "C" void kernel_launch(void* const* d_in, const int* in_sizes, int n_in,
                              void* d_out, int out_size, void* d_ws, size_t ws_size,
                              hipStream_t stream) {
  const float* x     = (const float*)d_in[0];
  const float* outp  = (const float*)d_in[1];
  const float* wnorm = (const float*)d_in[2];
  const float* ppre  = (const float*)d_in[3];
  const float* ppost = (const float*)d_in[4];
  const float* pres  = (const float*)d_in[5];
  const float* bpre  = (const float*)d_in[6];
  const float* bpost = (const float*)d_in[7];
  const float* bres  = (const float*)d_in[8];
  const float* apre  = (const float*)d_in[9];
  const float* apost = (const float*)d_in[10];
  const float* ares  = (const float*)d_in[11];
  const int*   aidx  = (const int*)d_in[12];

  float* agg = (float*)d_out;
  float* big = (float*)d_out + (size_t)TOKS * CCH;

  if (ws_size >= WS_NEED) {
    unsigned short* phiT = (unsigned short*)d_ws;
    float* gates = (float*)((char*)d_ws + GATES_OFF);
    hipLaunchKernelGGL(prep_phiT, dim3(128), dim3(256), 0, stream,
                       ppre, ppost, pres, phiT);
    hipLaunchKernelGGL(logits_gates, dim3(256), dim3(512), 0, stream,
                       x, wnorm, phiT, bpre, bpost, bres, apre, apost, ares, aidx, gates);
    hipLaunchKernelGGL(out_pass, dim3(4096), dim3(256), 0, stream, x, outp, gates, agg, big);
  } else {
    hipLaunchKernelGGL(lora_fused, dim3(2048), dim3(256), 0, stream,
                       x, outp, wnorm, ppre, ppost, pres,
                       bpre, bpost, bres, apre, apost, ares, aidx, agg, big);
  }
}

// Round 21
// 97.980 us; speedup vs baseline: 1.1387x; 1.0537x over previous
//
#include <hip/hip_runtime.h>

#define EPS 1e-5f
#define TOKS 4096
#define NCF 8192
#define CCH 2048

#define PHI_BYTES ((size_t)8 * 32 * 8192 * 2)            // 4 MB bf16 phiT (no w fold)
#define GATES_OFF PHI_BYTES                              // float[4096][32] = 512 KB
#define WS_NEED   (GATES_OFF + (size_t)TOKS * 32 * 4)

typedef __attribute__((ext_vector_type(8))) short bf16x8;
typedef __attribute__((ext_vector_type(4))) float f32x4;

__device__ __forceinline__ unsigned short f2bf(float f) {
  unsigned int u = __float_as_uint(f);
  u += 0x7FFFu + ((u >> 16) & 1u);
  return (unsigned short)(u >> 16);
}
__device__ __forceinline__ float bf2f(unsigned short s) {
  return __uint_as_float(((unsigned int)s) << 16);
}
__device__ __forceinline__ unsigned int pack2(float a, float b) {
  return (unsigned int)f2bf(a) | ((unsigned int)f2bf(b) << 16);
}

// ---------------- K0 v2: COALESCED transpose phi -> phiT (bf16, [A][32][8192]) ----------------
// rows 0-3 = pre cols, 4-7 = post cols, 8-23 = res cols, 24-31 = zero.
// Thread owns e0 = 2*gid..+1: reads are contiguous float4 runs (full cacheline use);
// writes are ushort2 per r-row -> 256 B contiguous per wave per row.   [r15-proven, 98.0 us total]
__global__ __launch_bounds__(256)
void prep_phiT(const float* __restrict__ pre, const float* __restrict__ post,
               const float* __restrict__ res, unsigned short* __restrict__ phiT) {
  const int gid = blockIdx.x * 256 + threadIdx.x;    // 8 * 4096 threads
  const int a = gid >> 12;
  const int e0 = (gid & 4095) * 2;

  // pre[e][0..3], e = e0, e0+1  (contiguous 32 B per thread)
  const float4 p0 = *(const float4*)(pre + ((size_t)a * NCF + e0) * 4);
  const float4 p1 = *(const float4*)(pre + ((size_t)a * NCF + e0) * 4 + 4);
  const float4 q0 = *(const float4*)(post + ((size_t)a * NCF + e0) * 4);
  const float4 q1 = *(const float4*)(post + ((size_t)a * NCF + e0) * 4 + 4);
  // res[e][0..15], e = e0, e0+1  (contiguous 128 B per thread)
  float r0[16], r1[16];
  #pragma unroll
  for (int j = 0; j < 4; ++j) {
    const float4 v = *(const float4*)(res + ((size_t)a * NCF + e0) * 16 + j * 4);
    r0[j*4+0] = v.x; r0[j*4+1] = v.y; r0[j*4+2] = v.z; r0[j*4+3] = v.w;
  }
  #pragma unroll
  for (int j = 0; j < 4; ++j) {
    const float4 v = *(const float4*)(res + ((size_t)a * NCF + e0) * 16 + 16 + j * 4);
    r1[j*4+0] = v.x; r1[j*4+1] = v.y; r1[j*4+2] = v.z; r1[j*4+3] = v.w;
  }

  unsigned short* base = phiT + (size_t)a * 32 * NCF + e0;
  const float pr0[4] = { p0.x, p0.y, p0.z, p0.w };
  const float pr1[4] = { p1.x, p1.y, p1.z, p1.w };
  const float po0[4] = { q0.x, q0.y, q0.z, q0.w };
  const float po1[4] = { q1.x, q1.y, q1.z, q1.w };
  #pragma unroll
  for (int r = 0; r < 4; ++r)
    *(unsigned int*)(base + (size_t)r * NCF) = pack2(pr0[r], pr1[r]);
  #pragma unroll
  for (int r = 0; r < 4; ++r)
    *(unsigned int*)(base + (size_t)(4 + r) * NCF) = pack2(po0[r], po1[r]);
  #pragma unroll
  for (int r = 0; r < 16; ++r)
    *(unsigned int*)(base + (size_t)(8 + r) * NCF) = pack2(r0[r], r1[r]);
  #pragma unroll
  for (int r = 24; r < 32; ++r)
    *(unsigned int*)(base + (size_t)r * NCF) = 0u;
}

// ---------------- K1: logits via MFMA + rms + sigmoid + Sinkhorn -> gates[tok][32] [r6-proven verbatim]
// 512 threads = 8 waves; wave w owns K-slice [w*1024, (w+1)*1024) for a 16-token tile.
__global__ __launch_bounds__(512, 1)
void logits_gates(const float* __restrict__ x,
                  const float* __restrict__ wnorm,
                  const unsigned short* __restrict__ phiT,
                  const float* __restrict__ b_pre, const float* __restrict__ b_post,
                  const float* __restrict__ b_res,
                  const float* __restrict__ a_pre, const float* __restrict__ a_post,
                  const float* __restrict__ a_res,
                  const int* __restrict__ aidx_arr,
                  float* __restrict__ gates) {
  __shared__ unsigned short xs[8][16 * 264];   // per-wave bf16 tile [16 tok][256 feat], row pad 264
  __shared__ float logits_s[8][16][32];
  __shared__ float ssq_s[8][16];

  const int tid = threadIdx.x;
  const int wave = tid >> 6, lane = tid & 63;
  const int tok0 = blockIdx.x * 16;
  const int aidx = aidx_arr[tok0 >> 10];
  const int kbase = wave * 1024;

  const float* xbase = x + (size_t)tok0 * NCF + kbase + lane * 4;
  const float* wbase = wnorm + (size_t)aidx * NCF + kbase + lane * 4;
  const unsigned short* pBbase =
      phiT + ((size_t)aidx * 32 + (lane & 15)) * NCF + kbase + (lane >> 4) * 8;

  f32x4 acc0 = {0.f, 0.f, 0.f, 0.f};
  f32x4 acc1 = {0.f, 0.f, 0.f, 0.f};
  float ssq[16];
  #pragma unroll
  for (int r = 0; r < 16; ++r) ssq[r] = 0.f;

  float4 xr[16];
  #pragma unroll
  for (int r = 0; r < 16; ++r) xr[r] = *(const float4*)(xbase + (size_t)r * NCF);

  for (int t = 0; t < 4; ++t) {
    const float4 wv = *(const float4*)(wbase + t * 256);
    // stage: ssq + bf16(w*x) -> LDS (wave-private, no barrier needed)
    #pragma unroll
    for (int r = 0; r < 16; ++r) {
      const float4 xv = xr[r];
      ssq[r] += xv.x * xv.x + xv.y * xv.y + xv.z * xv.z + xv.w * xv.w;
      ushort4 u = make_ushort4(f2bf(xv.x * wv.x), f2bf(xv.y * wv.y),
                               f2bf(xv.z * wv.z), f2bf(xv.w * wv.w));
      *(ushort4*)&xs[wave][r * 264 + lane * 4] = u;
    }
    if (t < 3) {
      #pragma unroll
      for (int r = 0; r < 16; ++r)
        xr[r] = *(const float4*)(xbase + (size_t)r * NCF + (t + 1) * 256);
    }
    const unsigned short* pB = pBbase + t * 256;
    #pragma unroll
    for (int s = 0; s < 8; ++s) {
      bf16x8 a = *(const bf16x8*)&xs[wave][(lane & 15) * 264 + s * 32 + (lane >> 4) * 8];
      bf16x8 b0 = *(const bf16x8*)(pB + s * 32);
      bf16x8 b1 = *(const bf16x8*)(pB + 16 * NCF + s * 32);
      acc0 = __builtin_amdgcn_mfma_f32_16x16x32_bf16(a, b0, acc0, 0, 0, 0);
      acc1 = __builtin_amdgcn_mfma_f32_16x16x32_bf16(a, b1, acc1, 0, 0, 0);
    }
  }

  // ssq reduce across 64 lanes
  #pragma unroll
  for (int r = 0; r < 16; ++r) {
    float v = ssq[r];
    #pragma unroll
    for (int m = 1; m <= 32; m <<= 1) v += __shfl_xor(v, m, 64);
    if (lane == 0) ssq_s[wave][r] = v;
  }
  // C frags -> LDS: D[m=tok][n=col], m=(lane>>4)*4+i, n=lane&15
  #pragma unroll
  for (int i = 0; i < 4; ++i) {
    logits_s[wave][(lane >> 4) * 4 + i][lane & 15] = acc0[i];
    logits_s[wave][(lane >> 4) * 4 + i][16 + (lane & 15)] = acc1[i];
  }
  __syncthreads();

  if (tid < 256) {
    // per-thread: tok = tid>>4 (0..15), cl = tid&15
    const int tok = tid >> 4, cl = tid & 15;
    float L0 = 0.f, L16 = 0.f, ssqt = 0.f;
    #pragma unroll
    for (int w = 0; w < 8; ++w) {
      L0 += logits_s[w][tok][cl];
      L16 += logits_s[w][tok][16 + cl];
      ssqt += ssq_s[w][tok];
    }
    const float invr = rsqrtf(ssqt * (1.f / NCF) + EPS);

    float* g = gates + (size_t)(tok0 + tok) * 32;
    if (cl < 4) {
      const float zp = a_pre[aidx] * L0 * invr + b_pre[(size_t)aidx * 4 + cl];
      g[cl] = 1.f / (1.f + __expf(-zp));
    } else if (cl < 8) {
      const float zq = a_post[aidx] * L0 * invr + b_post[(size_t)aidx * 4 + (cl - 4)];
      g[cl] = 2.f / (1.f + __expf(-zq));
    }
    // gather res logits: res[cl] = col 8+cl
    const float resv = __shfl_xor((cl & 8) ? L0 : L16, 8, 64);
    const float tl = a_res[aidx] * resv * invr + b_res[(size_t)aidx * 16 + cl];
    float m = __expf(tl);
    #pragma unroll
    for (int it = 0; it < 20; ++it) {
      float rs = m;
      rs += __shfl_xor(rs, 1, 64);
      rs += __shfl_xor(rs, 2, 64);
      m *= __builtin_amdgcn_rcpf(rs);
      float cs = m;
      cs += __shfl_xor(cs, 4, 64);
      cs += __shfl_xor(cs, 8, 64);
      m *= __builtin_amdgcn_rcpf(cs);
    }
    g[8 + cl] = m;
  }
}

// ---------------- K3: streaming output pass  [r6-proven verbatim] ----------------
__global__ __launch_bounds__(256)
void out_pass(const float* __restrict__ x, const float* __restrict__ outp,
              const float* __restrict__ gates,
              float* __restrict__ agg, float* __restrict__ big) {
  const int tok = blockIdx.x;
  const int tid = threadIdx.x;
  const float* g = gates + (size_t)tok * 32;
  float hp[4], hq[4], M[16];
  #pragma unroll
  for (int i = 0; i < 4; ++i) { hp[i] = g[i]; hq[i] = g[4 + i]; }
  #pragma unroll
  for (int i = 0; i < 16; ++i) M[i] = g[8 + i];

  const float* xrow = x + (size_t)tok * NCF;
  const float* orow = outp + (size_t)tok * CCH;
  float* arow = agg + (size_t)tok * CCH;
  float* brow = big + (size_t)tok * NCF;

  #pragma unroll
  for (int rep = 0; rep < 2; ++rep) {
    const int c = rep * 1024 + tid * 4;
    float4 xv[4];
    #pragma unroll
    for (int j = 0; j < 4; ++j) xv[j] = *(const float4*)(xrow + j * CCH + c);
    const float4 ov = *(const float4*)(orow + c);

    f32x4 ag;
    ag.x = hp[0]*xv[0].x + hp[1]*xv[1].x + hp[2]*xv[2].x + hp[3]*xv[3].x;
    ag.y = hp[0]*xv[0].y + hp[1]*xv[1].y + hp[2]*xv[2].y + hp[3]*xv[3].y;
    ag.z = hp[0]*xv[0].z + hp[1]*xv[1].z + hp[2]*xv[2].z + hp[3]*xv[3].z;
    ag.w = hp[0]*xv[0].w + hp[1]*xv[1].w + hp[2]*xv[2].w + hp[3]*xv[3].w;
    __builtin_nontemporal_store(ag, (f32x4*)(arow + c));

    #pragma unroll
    for (int i = 0; i < 4; ++i) {
      const float m0 = M[i*4+0], m1 = M[i*4+1], m2 = M[i*4+2], m3 = M[i*4+3];
      f32x4 o;
      o.x = m0*xv[0].x + m1*xv[1].x + m2*xv[2].x + m3*xv[3].x + hq[i]*ov.x;
      o.y = m0*xv[0].y + m1*xv[1].y + m2*xv[2].y + m3*xv[3].y + hq[i]*ov.y;
      o.z = m0*xv[0].z + m1*xv[1].z + m2*xv[2].z + m3*xv[3].z + hq[i]*ov.z;
      o.w = m0*xv[0].w + m1*xv[1].w + m2*xv[2].w + m3*xv[3].w + hq[i]*ov.w;
      __builtin_nontemporal_store(o, (f32x4*)(brow + i * CCH + c));
    }
  }
}

// ---------------- fallback: round-1 fused kernel (used if ws too small) ----------------
__global__ __launch_bounds__(256, 4)
void lora_fused(const float* __restrict__ x, const float* __restrict__ outp,
                const float* __restrict__ wnorm, const float* __restrict__ phi_pre,
                const float* __restrict__ phi_post, const float* __restrict__ phi_res,
                const float* __restrict__ b_pre, const float* __restrict__ b_post,
                const float* __restrict__ b_res, const float* __restrict__ a_pre,
                const float* __restrict__ a_post, const float* __restrict__ a_res,
                const int* __restrict__ aidx_arr, float* __restrict__ agg_out,
                float* __restrict__ big_out) {
  __shared__ unsigned short xsb[2][NCF];
  __shared__ float scratch[4][52];
  __shared__ float red[52];
  __shared__ float Hpre[2][4], Hpost[2][4], Msm[2][16];
  const int tid = threadIdx.x;
  const int tok0 = blockIdx.x * 2;
  const int aidx = aidx_arr[tok0 >> 10];
  const float* xr0 = x + (size_t)tok0 * NCF;
  const float* xr1 = xr0 + NCF;
  const float* wr = wnorm + (size_t)aidx * NCF;
  const float* pp = phi_pre + (size_t)aidx * NCF * 4;
  const float* pq = phi_post + (size_t)aidx * NCF * 4;
  const float* pr = phi_res + (size_t)aidx * NCF * 16;
  float acc[50];
  #pragma unroll
  for (int i = 0; i < 50; ++i) acc[i] = 0.f;
  for (int k = 0; k < 8; ++k) {
    const int f0 = (k * 256 + tid) * 4;
    const float4 w4 = *(const float4*)(wr + f0);
    const float4 xa = *(const float4*)(xr0 + f0);
    const float4 xb = *(const float4*)(xr1 + f0);
    acc[0] += xa.x*xa.x + xa.y*xa.y + xa.z*xa.z + xa.w*xa.w;
    acc[25] += xb.x*xb.x + xb.y*xb.y + xb.z*xb.z + xb.w*xb.w;
    float xw0[4] = { xa.x*w4.x, xa.y*w4.y, xa.z*w4.z, xa.w*w4.w };
    float xw1[4] = { xb.x*w4.x, xb.y*w4.y, xb.z*w4.z, xb.w*w4.w };
    *(ushort4*)&xsb[0][f0] = make_ushort4(f2bf(xa.x), f2bf(xa.y), f2bf(xa.z), f2bf(xa.w));
    *(ushort4*)&xsb[1][f0] = make_ushort4(f2bf(xb.x), f2bf(xb.y), f2bf(xb.z), f2bf(xb.w));
    #pragma unroll
    for (int d = 0; d < 4; ++d) {
      const int f = f0 + d;
      const float a0 = xw0[d], a1 = xw1[d];
      float col[24];
      const float4 P = *(const float4*)(pp + ((size_t)f << 2));
      const float4 Q = *(const float4*)(pq + ((size_t)f << 2));
      const float4 R0 = *(const float4*)(pr + ((size_t)f << 4));
      const float4 R1 = *(const float4*)(pr + ((size_t)f << 4) + 4);
      const float4 R2 = *(const float4*)(pr + ((size_t)f << 4) + 8);
      const float4 R3 = *(const float4*)(pr + ((size_t)f << 4) + 12);
      col[0]=P.x; col[1]=P.y; col[2]=P.z; col[3]=P.w;
      col[4]=Q.x; col[5]=Q.y; col[6]=Q.z; col[7]=Q.w;
      col[8]=R0.x; col[9]=R0.y; col[10]=R0.z; col[11]=R0.w;
      col[12]=R1.x; col[13]=R1.y; col[14]=R1.z; col[15]=R1.w;
      col[16]=R2.x; col[17]=R2.y; col[18]=R2.z; col[19]=R2.w;
      col[20]=R3.x; col[21]=R3.y; col[22]=R3.z; col[23]=R3.w;
      #pragma unroll
      for (int c = 0; c < 24; ++c) { acc[1 + c] += a0 * col[c]; acc[26 + c] += a1 * col[c]; }
    }
  }
  #pragma unroll
  for (int m = 1; m <= 32; m <<= 1) {
    #pragma unroll
    for (int v = 0; v < 50; ++v) acc[v] += __shfl_xor(acc[v], m, 64);
  }
  const int wave = tid >> 6, lane = tid & 63;
  if (lane == 0) {
    #pragma unroll
    for (int v = 0; v < 50; ++v) scratch[wave][v] = acc[v];
  }
  __syncthreads();
  if (tid < 50) red[tid] = scratch[0][tid] + scratch[1][tid] + scratch[2][tid] + scratch[3][tid];
  __syncthreads();
  if (tid < 32) {
    const int t = tid >> 4, l = tid & 15;
    const float invr = rsqrtf(red[t * 25] * (1.f / NCF) + EPS);
    const float tl = a_res[aidx] * red[t * 25 + 1 + 8 + l] * invr + b_res[(size_t)aidx * 16 + l];
    float m = __expf(tl);
    #pragma unroll
    for (int it = 0; it < 20; ++it) {
      float rs = m; rs += __shfl_xor(rs, 1, 64); rs += __shfl_xor(rs, 2, 64);
      m *= __builtin_amdgcn_rcpf(rs);
      float cs = m; cs += __shfl_xor(cs, 4, 64); cs += __shfl_xor(cs, 8, 64);
      m *= __builtin_amdgcn_rcpf(cs);
    }
    Msm[t][l] = m;
  } else if (tid < 40) {
    const int q = tid - 32, t = q >> 2, n = q & 3;
    const float invr = rsqrtf(red[t * 25] * (1.f / NCF) + EPS);
    const float zp = a_pre[aidx] * red[t * 25 + 1 + n] * invr + b_pre[(size_t)aidx * 4 + n];
    const float zq = a_post[aidx] * red[t * 25 + 1 + 4 + n] * invr + b_post[(size_t)aidx * 4 + n];
    Hpre[t][n] = 1.f / (1.f + __expf(-zp));
    Hpost[t][n] = 2.f / (1.f + __expf(-zq));
  }
  __syncthreads();
  #pragma unroll
  for (int t = 0; t < 2; ++t) {
    const int tok = tok0 + t;
    const float* orow = outp + (size_t)tok * CCH;
    float* arow = agg_out + (size_t)tok * CCH;
    float* brow = big_out + (size_t)tok * 4 * CCH;
    const float hp0 = Hpre[t][0], hp1 = Hpre[t][1], hp2 = Hpre[t][2], hp3 = Hpre[t][3];
    float Mr[16];
    #pragma unroll
    for (int i = 0; i < 16; ++i) Mr[i] = Msm[t][i];
    const float hq[4] = { Hpost[t][0], Hpost[t][1], Hpost[t][2], Hpost[t][3] };
    #pragma unroll
    for (int w = 0; w < 2; ++w) {
      const int c0 = (w * 256 + tid) * 4;
      float4 xv[4];
      #pragma unroll
      for (int n = 0; n < 4; ++n) {
        const ushort4 u = *(const ushort4*)&xsb[t][n * CCH + c0];
        xv[n] = make_float4(bf2f(u.x), bf2f(u.y), bf2f(u.z), bf2f(u.w));
      }
      const float4 ov = *(const float4*)(orow + c0);
      float4 ag;
      ag.x = hp0*xv[0].x + hp1*xv[1].x + hp2*xv[2].x + hp3*xv[3].x;
      ag.y = hp0*xv[0].y + hp1*xv[1].y + hp2*xv[2].y + hp3*xv[3].y;
      ag.z = hp0*xv[0].z + hp1*xv[1].z + hp2*xv[2].z + hp3*xv[3].z;
      ag.w = hp0*xv[0].w + hp1*xv[1].w + hp2*xv[2].w + hp3*xv[3].w;
      *(float4*)(arow + c0) = ag;
      #pragma unroll
      for (int i = 0; i < 4; ++i) {
        const float m0 = Mr[i*4+0], m1 = Mr[i*4+1], m2 = Mr[i*4+2], m3 = Mr[i*4+3];
        float4 o;
        o.x = m0*xv[0].x + m1*xv[1].x + m2*xv[2].x + m3*xv[3].x + hq[i]*ov.x;
        o.y = m0*xv[0].y + m1*xv[1].y + m2*xv[2].y + m3*xv[3].y + hq[i]*ov.y;
        o.z = m0*xv[0].z + m1*xv[1].z + m2*xv[2].z + m3*xv[3].z + hq[i]*ov.z;
        o.w = m0*xv[0].w + m1*xv[1].w + m2*xv[2].w + m3*xv[3].w + hq[i]*ov.w;
        *(float4*)(brow + (size_t)i * CCH + c0) = o;
      }
    }
  }
}

extern "C" void kernel_launch(void* const* d_in, const int* in_sizes, int n_in,
                              void* d_out, int out_size, void* d_ws, size_t ws_size,
                              hipStream_t stream) {
  const float* x     = (const float*)d_in[0];
  const float* outp  = (const float*)d_in[1];
  const float* wnorm = (const float*)d_in[2];
  const float* ppre  = (const float*)d_in[3];
  const float* ppost = (const float*)d_in[4];
  const float* pres  = (const float*)d_in[5];
  const float* bpre  = (const float*)d_in[6];
  const float* bpost = (const float*)d_in[7];
  const float* bres  = (const float*)d_in[8];
  const float* apre  = (const float*)d_in[9];
  const float* apost = (const float*)d_in[10];
  const float* ares  = (const float*)d_in[11];
  const int*   aidx  = (const int*)d_in[12];

  float* agg = (float*)d_out;
  float* big = (float*)d_out + (size_t)TOKS * CCH;

  if (ws_size >= WS_NEED) {
    unsigned short* phiT = (unsigned short*)d_ws;
    float* gates = (float*)((char*)d_ws + GATES_OFF);
    hipLaunchKernelGGL(prep_phiT, dim3(128), dim3(256), 0, stream,
                       ppre, ppost, pres, phiT);
    hipLaunchKernelGGL(logits_gates, dim3(256), dim3(512), 0, stream,
                       x, wnorm, phiT, bpre, bpost, bres, apre, apost, ares, aidx, gates);
    hipLaunchKernelGGL(out_pass, dim3(4096), dim3(256), 0, stream, x, outp, gates, agg, big);
  } else {
    hipLaunchKernelGGL(lora_fused, dim3(2048), dim3(256), 0, stream,
                       x, outp, wnorm, ppre, ppost, pres,
                       bpre, bpost, bres, apre, apost, ares, aidx, agg, big);
  }
}